// Round 11
// baseline (344.434 us; speedup 1.0000x reference)
//
#include <hip/hip_runtime.h>
#include <cstdint>

#define EPSF 1e-15f
#define MAXN (1.0f - 1e-5f)

typedef __attribute__((ext_vector_type(8))) short bf16x8;
typedef __attribute__((ext_vector_type(4))) float f32x4;

__device__ __forceinline__ float wsum64(float v) {
    v += __shfl_xor(v, 1);
    v += __shfl_xor(v, 2);
    v += __shfl_xor(v, 4);
    v += __shfl_xor(v, 8);
    v += __shfl_xor(v, 16);
    v += __shfl_xor(v, 32);
    return v;
}

__device__ __forceinline__ float dot4(float4 a, float4 b) {
    return a.x * b.x + a.y * b.y + a.z * b.z + a.w * b.w;
}

__device__ __forceinline__ float frcp(float x) {
    return __builtin_amdgcn_rcpf(x);
}

__device__ __forceinline__ float tanh_f(float x) {
    x = fminf(x, 10.f);
    float t = __expf(2.f * x);
    return (t - 1.f) * frcp(t + 1.f);
}

__device__ __forceinline__ float atanh_f(float x) {
    return 0.5f * __logf((1.f + x) * frcp(1.f - x));
}

__device__ __forceinline__ short f2bf(float f) {
    uint32_t b = __float_as_uint(f);
    b = (b + 0x7FFF + ((b >> 16) & 1)) >> 16;
    return (short)b;
}

__device__ __forceinline__ bf16x8 pack8(const float* __restrict__ p) {
    float4 lo = *(const float4*)p;
    float4 hi = *(const float4*)(p + 4);
    bf16x8 r;
    r[0] = f2bf(lo.x); r[1] = f2bf(lo.y); r[2] = f2bf(lo.z); r[3] = f2bf(lo.w);
    r[4] = f2bf(hi.x); r[5] = f2bf(hi.y); r[6] = f2bf(hi.z); r[7] = f2bf(hi.w);
    return r;
}

// hist+rank with per-XCD privatized histograms. Each workgroup increments its
// own XCD's copy with a WORKGROUP-scope atomic -> the RMW executes in the
// local (per-XCD) L2 instead of the memory-side device-atomic path.
// rank[e] = local_rank | (xcd << 24). Slot space: [ent | user | item], padded.
__global__ __launch_bounds__(256) void rank3_k(
        const int* __restrict__ kg_src, const int* __restrict__ iu_dst,
        const int* __restrict__ ui_dst,
        int* __restrict__ degP,
        int* __restrict__ rank_kg, int* __restrict__ rank_iu, int* __restrict__ rank_ui,
        int E_kg, int E_iu, int E_ui, int n_items, int N, int S1, int SU, int S3) {
    unsigned xcc;
    asm volatile("s_getreg_b32 %0, hwreg(HW_REG_XCC_ID)" : "=s"(xcc));
    xcc &= 7u;
    int* myDeg = degP + (size_t)xcc * S3;
    int tag = (int)(xcc << 24);
    long b0 = (long)blockIdx.x * 2048 + threadIdx.x;
#pragma unroll
    for (int j = 0; j < 8; ++j) {
        long t = b0 + (long)j * 256;
        if (t < E_kg) {
            int lr = __hip_atomic_fetch_add(&myDeg[kg_src[t]], 1,
                         __ATOMIC_RELAXED, __HIP_MEMORY_SCOPE_WORKGROUP);
            rank_kg[t] = lr | tag;
            continue;
        }
        long t2 = t - E_kg;
        if (t2 < E_iu) {
            int d = iu_dst[t2];
            if (d >= n_items && d < N) {
                int lr = __hip_atomic_fetch_add(&myDeg[S1 + d - n_items], 1,
                             __ATOMIC_RELAXED, __HIP_MEMORY_SCOPE_WORKGROUP);
                rank_iu[t2] = lr | tag;
            }
            continue;
        }
        long t3 = t2 - E_iu;
        if (t3 < E_ui) {
            int d = ui_dst[t3];
            if (d < n_items) {
                int lr = __hip_atomic_fetch_add(&myDeg[S1 + SU + d], 1,
                             __ATOMIC_RELAXED, __HIP_MEMORY_SCOPE_WORKGROUP);
                rank_ui[t3] = lr | tag;
            }
        }
    }
}

// Per-slot: sum the 8 XCD copies -> total degree; write exclusive per-XCD
// prefix back in place (xoff); block-scan + 1 atomic/block for segment bases.
__global__ __launch_bounds__(256) void reduce_alloc_k(
        int* __restrict__ degP, int* __restrict__ degT, int* __restrict__ base,
        int* __restrict__ gt_e, int* __restrict__ gt_u, int* __restrict__ gt_i,
        int S3, int Be, int Bu) {
    int slot = blockIdx.x * 256 + threadIdx.x;
    int c[8];
#pragma unroll
    for (int x = 0; x < 8; ++x) c[x] = degP[(size_t)x * S3 + slot];
    int tot = 0;
#pragma unroll
    for (int x = 0; x < 8; ++x) {
        int v = c[x];
        degP[(size_t)x * S3 + slot] = tot;
        tot += v;
    }
    degT[slot] = tot;

    int lane = threadIdx.x & 63, w = threadIdx.x >> 6;
    int inc = tot;
#pragma unroll
    for (int off = 1; off < 64; off <<= 1) {
        int u = __shfl_up(inc, off);
        if (lane >= off) inc += u;
    }
    __shared__ int wtot[4];
    __shared__ int bbase;
    if (lane == 63) wtot[w] = inc;
    __syncthreads();
    if (threadIdx.x == 0) {
        int s = 0;
#pragma unroll
        for (int i = 0; i < 4; ++i) { int x = wtot[i]; wtot[i] = s; s += x; }
        int* gt = (blockIdx.x < Be) ? gt_e : (blockIdx.x < Be + Bu) ? gt_u : gt_i;
        bbase = atomicAdd(gt, s);
    }
    __syncthreads();
    base[slot] = bbase + wtot[w] + inc - tot;
}

// ---------------- KG path ----------------

// Merged dots+chain: 4 lanes/edge coalesced reads, 2-step shfl reduce,
// fast-math chain 4x-redundant; slot = base[s] + xoff[xcd][s] + local_rank.
__global__ __launch_bounds__(256) void kg_edge_fused_k(const float* __restrict__ ent,
                          const float* __restrict__ rel,
                          const int* __restrict__ src,
                          const int* __restrict__ dst,
                          const int* __restrict__ typ,
                          const int* __restrict__ base,
                          const int* __restrict__ degP,
                          const int* __restrict__ rankv,
                          float4* __restrict__ payload,
                          int nE, int S3) {
    int w = blockIdx.x * 4 + (threadIdx.x >> 6);
    int l = threadIdx.x & 63;
    int e = w * 16 + (l >> 2);
    if (e >= nE) return;
    int j0 = l & 3;
    int s = src[e], d = dst[e], ty = typ[e] + 2;
    const float4* pu = (const float4*)(ent + (size_t)s * 64);
    const float4* pv = (const float4*)(ent + (size_t)d * 64);
    const float4* pr = (const float4*)(rel + (size_t)ty * 64);

    float uu = 0.f, vv = 0.f, rr = 0.f, uv = 0.f, ur = 0.f, vr = 0.f;
#pragma unroll
    for (int i = 0; i < 4; ++i) {
        float4 a = pu[4 * i + j0], b = pv[4 * i + j0], c = pr[4 * i + j0];
        uu += dot4(a, a); vv += dot4(b, b); rr += dot4(c, c);
        uv += dot4(a, b); ur += dot4(a, c); vr += dot4(b, c);
    }
#pragma unroll
    for (int m = 1; m < 4; m <<= 1) {
        uu += __shfl_xor(uu, m);
        vv += __shfl_xor(vv, m);
        rr += __shfl_xor(rr, m);
        uv += __shfl_xor(uv, m);
        ur += __shfl_xor(ur, m);
        vr += __shfl_xor(vr, m);
    }

    float n0 = sqrtf(fmaxf(uu, EPSF));
    float cp = tanh_f(n0) * frcp(n0);
    float p2 = cp * cp * uu;
    float om_p2 = 1.f - p2;
    float lam = 2.f * frcp(fmaxf(om_p2, EPSF));

    float nv = sqrtf(fmaxf(vv, EPSF));
    float cd = tanh_f(0.5f * lam * nv) * frcp(nv);
    float wd2 = cd * cd * vv;
    float pwd = cp * cd * uv;
    float iDd = frcp(fmaxf(1.f + 2.f * pwd + p2 * wd2, EPSF));
    float a1 = (1.f + 2.f * pwd + wd2) * cp * iDd;
    float b1 = om_p2 * cd * iDd;

    float nr = sqrtf(fmaxf(rr, EPSF));
    float cr = tanh_f(0.5f * lam * nr) * frcp(nr);
    float wr2 = cr * cr * rr;
    float pwr = cp * cr * ur;
    float iDr = frcp(fmaxf(1.f + 2.f * pwr + p2 * wr2, EPSF));
    float a2 = (1.f + 2.f * pwr + wr2) * cp * iDr;
    float c2 = om_p2 * cr * iDr;

    float x2 = a1 * a1 * uu + 2.f * a1 * b1 * uv + b1 * b1 * vv;
    float y2 = a2 * a2 * uu + 2.f * a2 * c2 * ur + c2 * c2 * rr;
    float xy = a1 * a2 * uu + a1 * c2 * ur + b1 * a2 * uv + b1 * c2 * vr;
    float iden = frcp(fmaxf(1.f + 2.f * xy + x2 * y2, EPSF));
    float E = (1.f + 2.f * xy + y2) * iden;
    float F = (1.f - x2) * iden;
    float zu = E * a1 + F * a2;
    float zv = E * b1;
    float zr = F * c2;

    float z2 = zu * zu * uu + zv * zv * vv + zr * zr * rr
             + 2.f * (zu * zv * uv + zu * zr * ur + zv * zr * vr);
    float nz = sqrtf(fmaxf(z2, EPSF));
    if (nz > MAXN) {
        float sc = MAXN * frcp(nz);
        zu *= sc; zv *= sc; zr *= sc;
        z2 *= sc * sc;
    }

    float mxy = -cp * (zu * uu + zv * uv + zr * ur);
    float idenl = frcp(fmaxf(1.f + 2.f * mxy + p2 * z2, EPSF));
    float G = (1.f + 2.f * mxy + z2) * idenl;
    float H = om_p2 * idenl;
    float su = -G * cp + H * zu;
    float sv = H * zv;
    float sr = H * zr;

    float ns2 = su * su * uu + sv * sv * vv + sr * sr * rr
              + 2.f * (su * sv * uv + su * sr * ur + sv * sr * vr);
    float ns = sqrtf(fmaxf(ns2, EPSF));
    float k = fmaxf(om_p2, EPSF) * atanh_f(fminf(ns, MAXN)) * frcp(ns);

    if (j0 == 0) {
        int r = rankv[e];
        int pos = base[s] + degP[(size_t)(((unsigned)r) >> 24) * S3 + s]
                + (r & 0xFFFFFF);
        payload[pos] = make_float4(k * sv, k * sr, k * su,
                                   __int_as_float(d | (ty << 18)));
    }
}

// Wave-per-entity CSR gather, 4x unrolled; also emits item-row norms.
__global__ void kg_gather_k(const float* __restrict__ ent,
                            const float* __restrict__ rel,
                            const int* __restrict__ degT,
                            const int* __restrict__ base,
                            const float4* __restrict__ payload,
                            float* __restrict__ out_final,
                            float* __restrict__ out_items,
                            float* __restrict__ normv,
                            int n_items, int n) {
    int i = blockIdx.x * (blockDim.x >> 6) + (threadIdx.x >> 6);
    if (i >= n) return;
    int l = threadIdx.x & 63;
    int b = base[i], dg = degT[i];
    float acc = 0.f, as = 0.f;
    int q = 0;
    for (; q + 4 <= dg; q += 4) {
        float4 p0 = payload[b + q];
        float4 p1 = payload[b + q + 1];
        float4 p2 = payload[b + q + 2];
        float4 p3 = payload[b + q + 3];
        int w0 = __float_as_int(p0.w), w1 = __float_as_int(p1.w);
        int w2 = __float_as_int(p2.w), w3 = __float_as_int(p3.w);
        float v0 = ent[(size_t)(w0 & 0x3FFFF) * 64 + l];
        float r0 = rel[(size_t)(w0 >> 18) * 64 + l];
        float v1 = ent[(size_t)(w1 & 0x3FFFF) * 64 + l];
        float r1 = rel[(size_t)(w1 >> 18) * 64 + l];
        float v2 = ent[(size_t)(w2 & 0x3FFFF) * 64 + l];
        float r2 = rel[(size_t)(w2 >> 18) * 64 + l];
        float v3 = ent[(size_t)(w3 & 0x3FFFF) * 64 + l];
        float r3 = rel[(size_t)(w3 >> 18) * 64 + l];
        acc += p0.x * v0 + p0.y * r0 + p1.x * v1 + p1.y * r1;
        acc += p2.x * v2 + p2.y * r2 + p3.x * v3 + p3.y * r3;
        as += (p0.z + p1.z) + (p2.z + p3.z);
    }
    for (; q < dg; ++q) {
        float4 p = payload[b + q];
        int w = __float_as_int(p.w);
        acc += p.x * ent[(size_t)(w & 0x3FFFF) * 64 + l]
             + p.y * rel[(size_t)(w >> 18) * 64 + l];
        as += p.z;
    }
    float v = (acc + as * ent[(size_t)i * 64 + l]) * frcp(fmaxf((float)dg, 1.f));
    if (i < n_items) {
        out_items[(size_t)i * 64 + l] = v;
        float s2 = wsum64(v * v);
        if (l == 0) normv[i] = s2;
    } else {
        out_final[(size_t)i * 64 + l] = v;
    }
}

// norms for the user half of cat_nodes
__global__ void user_norm_k(const float* __restrict__ user, float* __restrict__ normv,
                            int n_items, int n_usr) {
    int j = blockIdx.x * (blockDim.x >> 6) + (threadIdx.x >> 6);
    if (j >= n_usr) return;
    int l = threadIdx.x & 63;
    float c = user[(size_t)j * 64 + l];
    float s = wsum64(c * c);
    if (l == 0) normv[n_items + j] = s;
}

// ---------------- CF path ----------------

// iu scatter (no atomics): slot = S1 + d - n_items
__global__ void iu_scat_k(const int* __restrict__ srcA, const int* __restrict__ dstA,
                          const int* __restrict__ base, const int* __restrict__ degP,
                          const int* __restrict__ rankv,
                          int* __restrict__ payload,
                          int n_items, int N, int nE, int S1, int S3) {
    int e = blockIdx.x * blockDim.x + threadIdx.x;
    if (e >= nE) return;
    int d = dstA[e];
    if (d < n_items || d >= N) return;
    int slot = S1 + d - n_items;
    int r = rankv[e];
    payload[base[slot] + degP[(size_t)(((unsigned)r) >> 24) * S3 + slot]
            + (r & 0xFFFFFF)] = srcA[e];
}

// ui scatter (no atomics): slot = S1 + SU + d ; payload = {src, 1/(norm+1e-6)}
__global__ void ui_scat_k(const int* __restrict__ srcA, const int* __restrict__ dstA,
                          const float* __restrict__ normv,
                          const int* __restrict__ base, const int* __restrict__ degP,
                          const int* __restrict__ rankv,
                          float2* __restrict__ payload,
                          int n_items, int nE, int S1SU, int S3) {
    int e = blockIdx.x * blockDim.x + threadIdx.x;
    if (e >= nE) return;
    int d = dstA[e];
    if (d >= n_items) return;
    int s = srcA[e];
    int slot = S1SU + d;
    int r = rankv[e];
    payload[base[slot] + degP[(size_t)(((unsigned)r) >> 24) * S3 + slot]
            + (r & 0xFFFFFF)] = make_float2(__int_as_float(s), frcp(normv[s] + 1e-6f));
}

// wave-per-user gather, 8x unrolled: out_u = (sum cat[src]) / deg
__global__ void iu_gather_k(const float* __restrict__ items, const float* __restrict__ user,
                            const int* __restrict__ degT, const int* __restrict__ base,
                            const int* __restrict__ payload,
                            float* __restrict__ out_u, int n_items, int n, int S1) {
    int i = blockIdx.x * (blockDim.x >> 6) + (threadIdx.x >> 6);
    if (i >= n) return;
    int l = threadIdx.x & 63;
    int b = base[S1 + i], dg = degT[S1 + i];
    float acc = 0.f;
    int q = 0;
    for (; q + 8 <= dg; q += 8) {
        float vs[8];
#pragma unroll
        for (int j = 0; j < 8; ++j) {
            int s0 = payload[b + q + j];
            vs[j] = (s0 < n_items) ? items[(size_t)s0 * 64 + l]
                                   : user[(size_t)(s0 - n_items) * 64 + l];
        }
#pragma unroll
        for (int j = 0; j < 8; ++j) acc += vs[j];
    }
    for (; q < dg; ++q) {
        int s0 = payload[b + q];
        acc += (s0 < n_items) ? items[(size_t)s0 * 64 + l]
                              : user[(size_t)(s0 - n_items) * 64 + l];
    }
    out_u[(size_t)i * 64 + l] = acc * frcp(fmaxf((float)dg, 1.f));
}

// wave-per-item gather, 8x unrolled: icf = norm[i]*(sum f_e*cat[src_e])/deg
__global__ void ui_gather_k(const float* __restrict__ items, const float* __restrict__ user,
                            const float* __restrict__ normv,
                            const int* __restrict__ degT, const int* __restrict__ base,
                            const float2* __restrict__ payload,
                            float* __restrict__ icf, int n_items, int n, int S1SU) {
    int i = blockIdx.x * (blockDim.x >> 6) + (threadIdx.x >> 6);
    if (i >= n) return;
    int l = threadIdx.x & 63;
    int b = base[S1SU + i], dg = degT[S1SU + i];
    float acc = 0.f;
    int q = 0;
    for (; q + 8 <= dg; q += 8) {
        float2 ps[8];
        float vs[8];
#pragma unroll
        for (int j = 0; j < 8; ++j) ps[j] = payload[b + q + j];
#pragma unroll
        for (int j = 0; j < 8; ++j) {
            int s0 = __float_as_int(ps[j].x);
            vs[j] = (s0 < n_items) ? items[(size_t)s0 * 64 + l]
                                   : user[(size_t)(s0 - n_items) * 64 + l];
        }
#pragma unroll
        for (int j = 0; j < 8; ++j) acc += ps[j].y * vs[j];
    }
    for (; q < dg; ++q) {
        float2 p0 = payload[b + q];
        int s0 = __float_as_int(p0.x);
        acc += p0.y * ((s0 < n_items) ? items[(size_t)s0 * 64 + l]
                                      : user[(size_t)(s0 - n_items) * 64 + l]);
    }
    icf[(size_t)i * 64 + l] = normv[i] * acc * frcp(fmaxf((float)dg, 1.f));
}

// MFMA gate+fusion: acc = [oi|cf] @ [W1;W2]^T (bf16), out = g*oi + (1-g)*cf.
__global__ __launch_bounds__(256) void fusion_mfma_k(const float* __restrict__ items,
                          const float* __restrict__ icf,
                          const float* __restrict__ W1, const float* __restrict__ W2,
                          float* __restrict__ outf, int n_items) {
    int lane = threadIdx.x & 63;
    int row0 = blockIdx.x * 64 + (threadIdx.x >> 6) * 16;
    int r = lane & 15, g = lane >> 4;

    int arow = row0 + r;
    size_t rbase = (size_t)(arow < n_items ? arow : 0) * 64;

    bf16x8 afrag[4];
#pragma unroll
    for (int s = 0; s < 4; ++s) {
        int kb = s * 32 + g * 8;
        const float* p = (kb < 64) ? (items + rbase + kb) : (icf + rbase + kb - 64);
        afrag[s] = pack8(p);
    }

    bf16x8 bfrag[4][4];
#pragma unroll
    for (int c = 0; c < 4; ++c) {
        int col = c * 16 + r;
#pragma unroll
        for (int s = 0; s < 4; ++s) {
            int kb = s * 32 + g * 8;
            const float* p = (kb < 64) ? (W1 + col * 64 + kb) : (W2 + col * 64 + kb - 64);
            bfrag[c][s] = pack8(p);
        }
    }

    f32x4 acc[4] = {{0.f,0.f,0.f,0.f},{0.f,0.f,0.f,0.f},
                    {0.f,0.f,0.f,0.f},{0.f,0.f,0.f,0.f}};
#pragma unroll
    for (int s = 0; s < 4; ++s)
#pragma unroll
        for (int c = 0; c < 4; ++c)
            acc[c] = __builtin_amdgcn_mfma_f32_16x16x32_bf16(afrag[s], bfrag[c][s],
                                                             acc[c], 0, 0, 0);

#pragma unroll
    for (int c = 0; c < 4; ++c) {
        int col = c * 16 + r;
#pragma unroll
        for (int q = 0; q < 4; ++q) {
            int orow = row0 + g * 4 + q;
            if (orow < n_items) {
                size_t off = (size_t)orow * 64 + col;
                float oi = items[off], cf = icf[off];
                float gate = frcp(1.f + __expf(-acc[c][q]));
                outf[off] = gate * oi + (1.f - gate) * cf;
            }
        }
    }
}

extern "C" void kernel_launch(void* const* d_in, const int* in_sizes, int n_in,
                              void* d_out, int out_size, void* d_ws, size_t ws_size,
                              hipStream_t stream) {
    const float* ent    = (const float*)d_in[0];
    const float* usr    = (const float*)d_in[1];
    const float* rel    = (const float*)d_in[2];
    const float* W1     = (const float*)d_in[3];
    const float* W2     = (const float*)d_in[4];
    const int*   kg_src = (const int*)d_in[5];
    const int*   kg_dst = (const int*)d_in[6];
    const int*   kg_typ = (const int*)d_in[7];
    const int*   iu_src = (const int*)d_in[8];
    const int*   iu_dst = (const int*)d_in[9];
    const int*   ui_src = (const int*)d_in[10];
    const int*   ui_dst = (const int*)d_in[11];

    const int n_ent   = in_sizes[0] / 64;
    const int n_usr   = in_sizes[1] / 64;
    const int E_kg    = in_sizes[5];
    const int E_iu    = in_sizes[8];
    const int E_ui    = in_sizes[10];
    const int n_items = (out_size - in_sizes[0] - in_sizes[1]) / 64;
    const int N       = n_items + n_usr;

    // padded slot space: [ent | user | item], each 256-aligned
    const int S1 = ((n_ent + 255) / 256) * 256;
    const int SU = ((n_usr + 255) / 256) * 256;
    const int SI = ((n_items + 255) / 256) * 256;
    const int S3 = S1 + SU + SI;
    const int Be = S1 / 256, Bu = SU / 256, Bi = SI / 256;

    float* out_final = (float*)d_out;                        // (n_ent,64)
    float* out_u     = out_final + (size_t)n_ent * 64;       // (n_usr,64)
    float* out_items = out_u + (size_t)n_usr * 64;           // (n_items,64)

    // rank arrays live in the out_u chunk (12.8MB >= 8.8MB), consumed by
    // kg_edge/iu_scat/ui_scat, all BEFORE iu_gather_k writes out_u.
    int* rank_kg = (int*)out_u;
    int* rank_iu = rank_kg + E_kg;
    int* rank_ui = rank_iu + E_iu;

    float* ws = (float*)d_ws;
    size_t o = 0;
    // --- contiguous zero block: 8 XCD-private histograms + 3 gt counters ---
    int*   degP = (int*)(ws + o);   o += (size_t)8 * S3;
    int*   gt_e = (int*)(ws + o);   o += 1;
    int*   gt_u = (int*)(ws + o);   o += 1;
    int*   gt_i = (int*)(ws + o);   o += 1;
    size_t zero_len = ((size_t)8 * S3 + 3) * sizeof(int);
    // --- written by reduce_alloc, no zeroing ---
    int*   degT = (int*)(ws + o);   o += S3;
    int*   basep= (int*)(ws + o);   o += S3;
    o = (o + 3) & ~(size_t)3;                      // 16B align
    float4* pay_kg = (float4*)(ws + o); o += (size_t)E_kg * 4;
    int*    pay_iu = (int*)(ws + o);    o += E_iu;
    o = (o + 1) & ~(size_t)1;                      // 8B align
    float2* pay_ui = (float2*)(ws + o); o += (size_t)E_ui * 2;
    float* normv = ws + o;          o += N;
    o = (o + 3) & ~(size_t)3;                      // 16B align
    float* icf   = ws + o;          o += (size_t)n_items * 64;

    hipMemsetAsync(degP, 0, zero_len, stream);

    // hist+rank (per-XCD privatized), then 8-way reduce + scan-based alloc
    long tot_hist = (long)E_kg + E_iu + E_ui;
    rank3_k<<<(int)((tot_hist + 2047) / 2048), 256, 0, stream>>>(
        kg_src, iu_dst, ui_dst, degP,
        rank_kg, rank_iu, rank_ui, E_kg, E_iu, E_ui, n_items, N, S1, SU, S3);
    reduce_alloc_k<<<Be + Bu + Bi, 256, 0, stream>>>(degP, degT, basep,
                                                     gt_e, gt_u, gt_i, S3, Be, Bu);

    // KG compute
    kg_edge_fused_k<<<(E_kg + 63) / 64, 256, 0, stream>>>(ent, rel, kg_src, kg_dst,
                                                          kg_typ, basep, degP, rank_kg,
                                                          pay_kg, E_kg, S3);
    kg_gather_k<<<(n_ent + 3) / 4, 256, 0, stream>>>(ent, rel, degT, basep, pay_kg,
                                                     out_final, out_items, normv,
                                                     n_items, n_ent);
    user_norm_k<<<(n_usr + 3) / 4, 256, 0, stream>>>(usr, normv, n_items, n_usr);

    // CF scatters (atomic-free), then gathers (iu_gather overwrites out_u AFTER
    // all rank consumers have run)
    iu_scat_k<<<(E_iu + 255) / 256, 256, 0, stream>>>(iu_src, iu_dst, basep, degP,
                                                      rank_iu, pay_iu, n_items, N,
                                                      E_iu, S1, S3);
    ui_scat_k<<<(E_ui + 255) / 256, 256, 0, stream>>>(ui_src, ui_dst, normv, basep,
                                                      degP, rank_ui, pay_ui, n_items,
                                                      E_ui, S1 + SU, S3);
    iu_gather_k<<<(n_usr + 3) / 4, 256, 0, stream>>>(out_items, usr, degT, basep,
                                                     pay_iu, out_u, n_items, n_usr, S1);
    ui_gather_k<<<(n_items + 3) / 4, 256, 0, stream>>>(out_items, usr, normv, degT,
                                                       basep, pay_ui, icf, n_items,
                                                       n_items, S1 + SU);
    fusion_mfma_k<<<(n_items + 63) / 64, 256, 0, stream>>>(out_items, icf, W1, W2,
                                                           out_final, n_items);
}

// Round 12
// 310.246 us; speedup vs baseline: 1.1102x; 1.1102x over previous
//
#include <hip/hip_runtime.h>
#include <cstdint>

#define EPSF 1e-15f
#define MAXN (1.0f - 1e-5f)

typedef __attribute__((ext_vector_type(8))) short bf16x8;
typedef __attribute__((ext_vector_type(4))) float f32x4;

__device__ __forceinline__ float wsum64(float v) {
    v += __shfl_xor(v, 1);
    v += __shfl_xor(v, 2);
    v += __shfl_xor(v, 4);
    v += __shfl_xor(v, 8);
    v += __shfl_xor(v, 16);
    v += __shfl_xor(v, 32);
    return v;
}

__device__ __forceinline__ float dot4(float4 a, float4 b) {
    return a.x * b.x + a.y * b.y + a.z * b.z + a.w * b.w;
}

__device__ __forceinline__ float frcp(float x) {
    return __builtin_amdgcn_rcpf(x);
}

__device__ __forceinline__ float tanh_f(float x) {
    x = fminf(x, 10.f);
    float t = __expf(2.f * x);
    return (t - 1.f) * frcp(t + 1.f);
}

__device__ __forceinline__ float atanh_f(float x) {
    return 0.5f * __logf((1.f + x) * frcp(1.f - x));
}

__device__ __forceinline__ short f2bf(float f) {
    uint32_t b = __float_as_uint(f);
    b = (b + 0x7FFF + ((b >> 16) & 1)) >> 16;
    return (short)b;
}

__device__ __forceinline__ bf16x8 pack8(const float* __restrict__ p) {
    float4 lo = *(const float4*)p;
    float4 hi = *(const float4*)(p + 4);
    bf16x8 r;
    r[0] = f2bf(lo.x); r[1] = f2bf(lo.y); r[2] = f2bf(lo.z); r[3] = f2bf(lo.w);
    r[4] = f2bf(hi.x); r[5] = f2bf(hi.y); r[6] = f2bf(hi.z); r[7] = f2bf(hi.w);
    return r;
}

// Combined hist+rank for all three graphs: rank[e] = old count (the CSR rank).
__global__ __launch_bounds__(256) void rank3_k(
        const int* __restrict__ kg_src, const int* __restrict__ iu_dst,
        const int* __restrict__ ui_dst,
        int* __restrict__ deg_e, int* __restrict__ deg_u, int* __restrict__ deg_i,
        int* __restrict__ rank_kg, int* __restrict__ rank_iu, int* __restrict__ rank_ui,
        int E_kg, int E_iu, int E_ui, int n_items, int N) {
    long b0 = (long)blockIdx.x * 2048 + threadIdx.x;
#pragma unroll
    for (int j = 0; j < 8; ++j) {
        long t = b0 + j * 256;
        if (t < E_kg) {
            rank_kg[t] = atomicAdd(&deg_e[kg_src[t]], 1);
            continue;
        }
        t -= E_kg;
        if (t < E_iu) {
            int d = iu_dst[t];
            if (d >= n_items && d < N) rank_iu[t] = atomicAdd(&deg_u[d - n_items], 1);
            continue;
        }
        t -= E_iu;
        if (t < E_ui) {
            int d = ui_dst[t];
            if (d < n_items) rank_ui[t] = atomicAdd(&deg_i[d], 1);
        }
    }
}

// CSR base allocation via block scan + 1 atomic per block (order-free bases).
__global__ __launch_bounds__(256) void alloc3_k(
        const int* __restrict__ deg_e, const int* __restrict__ deg_u,
        const int* __restrict__ deg_i,
        int* __restrict__ base_e, int* __restrict__ base_u, int* __restrict__ base_i,
        int* __restrict__ gt_e, int* __restrict__ gt_u, int* __restrict__ gt_i,
        int n_ent, int n_usr, int n_items, int Be, int Bu) {
    const int* deg; int* base; int* gt; int n; int boff;
    int b = blockIdx.x;
    if (b < Be)           { deg = deg_e; base = base_e; gt = gt_e; n = n_ent;   boff = b; }
    else if (b < Be + Bu) { deg = deg_u; base = base_u; gt = gt_u; n = n_usr;   boff = b - Be; }
    else                  { deg = deg_i; base = base_i; gt = gt_i; n = n_items; boff = b - Be - Bu; }

    int t = boff * 256 + threadIdx.x;
    int v = (t < n) ? deg[t] : 0;
    int lane = threadIdx.x & 63, w = threadIdx.x >> 6;

    int inc = v;
#pragma unroll
    for (int off = 1; off < 64; off <<= 1) {
        int u = __shfl_up(inc, off);
        if (lane >= off) inc += u;
    }

    __shared__ int wtot[4];
    __shared__ int bbase;
    if (lane == 63) wtot[w] = inc;
    __syncthreads();
    if (threadIdx.x == 0) {
        int s = 0;
#pragma unroll
        for (int i = 0; i < 4; ++i) { int x = wtot[i]; wtot[i] = s; s += x; }
        bbase = atomicAdd(gt, s);
    }
    __syncthreads();
    if (t < n) base[t] = bbase + wtot[w] + inc - v;
}

// ---------------- KG path ----------------

// Scatter packed edge records into CSR slot order: rec[slot] = {src, dst|typ<<18}.
// Coalesced reads; scattered 8B writes are absorbed by L2 (6.4MB target).
__global__ void rec_scat_k(const int* __restrict__ src, const int* __restrict__ dst,
                           const int* __restrict__ typ,
                           const int* __restrict__ base, const int* __restrict__ rankv,
                           int2* __restrict__ rec, int nE) {
    int e = blockIdx.x * blockDim.x + threadIdx.x;
    if (e >= nE) return;
    int s = src[e];
    rec[base[s] + rankv[e]] = make_int2(s, dst[e] | ((typ[e] + 2) << 18));
}

// Merged dots+chain in CSR (slot) order: a node's ~8 edges occupy consecutive
// slots, so the u-row is L1/L2-hot across the wave; payload writes coalesced.
// 4 lanes/edge coalesced row reads, 2-step shfl reduce, fast-math chain.
__global__ __launch_bounds__(256) void kg_edge_fused_k(const float* __restrict__ ent,
                          const float* __restrict__ rel,
                          const int2* __restrict__ rec,
                          float4* __restrict__ payload,
                          int nE) {
    int w = blockIdx.x * 4 + (threadIdx.x >> 6);
    int l = threadIdx.x & 63;
    int slot = w * 16 + (l >> 2);
    if (slot >= nE) return;
    int j0 = l & 3;
    int2 rc = rec[slot];
    int s = rc.x, d = rc.y & 0x3FFFF, ty = rc.y >> 18;
    const float4* pu = (const float4*)(ent + (size_t)s * 64);
    const float4* pv = (const float4*)(ent + (size_t)d * 64);
    const float4* pr = (const float4*)(rel + (size_t)ty * 64);

    float uu = 0.f, vv = 0.f, rr = 0.f, uv = 0.f, ur = 0.f, vr = 0.f;
#pragma unroll
    for (int i = 0; i < 4; ++i) {
        float4 a = pu[4 * i + j0], b = pv[4 * i + j0], c = pr[4 * i + j0];
        uu += dot4(a, a); vv += dot4(b, b); rr += dot4(c, c);
        uv += dot4(a, b); ur += dot4(a, c); vr += dot4(b, c);
    }
#pragma unroll
    for (int m = 1; m < 4; m <<= 1) {
        uu += __shfl_xor(uu, m);
        vv += __shfl_xor(vv, m);
        rr += __shfl_xor(rr, m);
        uv += __shfl_xor(uv, m);
        ur += __shfl_xor(ur, m);
        vr += __shfl_xor(vr, m);
    }

    float n0 = sqrtf(fmaxf(uu, EPSF));
    float cp = tanh_f(n0) * frcp(n0);
    float p2 = cp * cp * uu;
    float om_p2 = 1.f - p2;
    float lam = 2.f * frcp(fmaxf(om_p2, EPSF));

    float nv = sqrtf(fmaxf(vv, EPSF));
    float cd = tanh_f(0.5f * lam * nv) * frcp(nv);
    float wd2 = cd * cd * vv;
    float pwd = cp * cd * uv;
    float iDd = frcp(fmaxf(1.f + 2.f * pwd + p2 * wd2, EPSF));
    float a1 = (1.f + 2.f * pwd + wd2) * cp * iDd;
    float b1 = om_p2 * cd * iDd;

    float nr = sqrtf(fmaxf(rr, EPSF));
    float cr = tanh_f(0.5f * lam * nr) * frcp(nr);
    float wr2 = cr * cr * rr;
    float pwr = cp * cr * ur;
    float iDr = frcp(fmaxf(1.f + 2.f * pwr + p2 * wr2, EPSF));
    float a2 = (1.f + 2.f * pwr + wr2) * cp * iDr;
    float c2 = om_p2 * cr * iDr;

    float x2 = a1 * a1 * uu + 2.f * a1 * b1 * uv + b1 * b1 * vv;
    float y2 = a2 * a2 * uu + 2.f * a2 * c2 * ur + c2 * c2 * rr;
    float xy = a1 * a2 * uu + a1 * c2 * ur + b1 * a2 * uv + b1 * c2 * vr;
    float iden = frcp(fmaxf(1.f + 2.f * xy + x2 * y2, EPSF));
    float E = (1.f + 2.f * xy + y2) * iden;
    float F = (1.f - x2) * iden;
    float zu = E * a1 + F * a2;
    float zv = E * b1;
    float zr = F * c2;

    float z2 = zu * zu * uu + zv * zv * vv + zr * zr * rr
             + 2.f * (zu * zv * uv + zu * zr * ur + zv * zr * vr);
    float nz = sqrtf(fmaxf(z2, EPSF));
    if (nz > MAXN) {
        float sc = MAXN * frcp(nz);
        zu *= sc; zv *= sc; zr *= sc;
        z2 *= sc * sc;
    }

    float mxy = -cp * (zu * uu + zv * uv + zr * ur);
    float idenl = frcp(fmaxf(1.f + 2.f * mxy + p2 * z2, EPSF));
    float G = (1.f + 2.f * mxy + z2) * idenl;
    float H = om_p2 * idenl;
    float su = -G * cp + H * zu;
    float sv = H * zv;
    float sr = H * zr;

    float ns2 = su * su * uu + sv * sv * vv + sr * sr * rr
              + 2.f * (su * sv * uv + su * sr * ur + sv * sr * vr);
    float ns = sqrtf(fmaxf(ns2, EPSF));
    float k = fmaxf(om_p2, EPSF) * atanh_f(fminf(ns, MAXN)) * frcp(ns);

    if (j0 == 0) {
        payload[slot] = make_float4(k * sv, k * sr, k * su, __int_as_float(rc.y));
    }
}

// Wave-per-entity CSR gather, 4x unrolled; also emits item-row norms.
__global__ void kg_gather_k(const float* __restrict__ ent,
                            const float* __restrict__ rel,
                            const int* __restrict__ deg,
                            const int* __restrict__ base,
                            const float4* __restrict__ payload,
                            float* __restrict__ out_final,
                            float* __restrict__ out_items,
                            float* __restrict__ normv,
                            int n_items, int n) {
    int i = blockIdx.x * (blockDim.x >> 6) + (threadIdx.x >> 6);
    if (i >= n) return;
    int l = threadIdx.x & 63;
    int b = base[i], dg = deg[i];
    float acc = 0.f, as = 0.f;
    int q = 0;
    for (; q + 4 <= dg; q += 4) {
        float4 p0 = payload[b + q];
        float4 p1 = payload[b + q + 1];
        float4 p2 = payload[b + q + 2];
        float4 p3 = payload[b + q + 3];
        int w0 = __float_as_int(p0.w), w1 = __float_as_int(p1.w);
        int w2 = __float_as_int(p2.w), w3 = __float_as_int(p3.w);
        float v0 = ent[(size_t)(w0 & 0x3FFFF) * 64 + l];
        float r0 = rel[(size_t)(w0 >> 18) * 64 + l];
        float v1 = ent[(size_t)(w1 & 0x3FFFF) * 64 + l];
        float r1 = rel[(size_t)(w1 >> 18) * 64 + l];
        float v2 = ent[(size_t)(w2 & 0x3FFFF) * 64 + l];
        float r2 = rel[(size_t)(w2 >> 18) * 64 + l];
        float v3 = ent[(size_t)(w3 & 0x3FFFF) * 64 + l];
        float r3 = rel[(size_t)(w3 >> 18) * 64 + l];
        acc += p0.x * v0 + p0.y * r0 + p1.x * v1 + p1.y * r1;
        acc += p2.x * v2 + p2.y * r2 + p3.x * v3 + p3.y * r3;
        as += (p0.z + p1.z) + (p2.z + p3.z);
    }
    for (; q < dg; ++q) {
        float4 p = payload[b + q];
        int w = __float_as_int(p.w);
        acc += p.x * ent[(size_t)(w & 0x3FFFF) * 64 + l]
             + p.y * rel[(size_t)(w >> 18) * 64 + l];
        as += p.z;
    }
    float v = (acc + as * ent[(size_t)i * 64 + l]) * frcp(fmaxf((float)dg, 1.f));
    if (i < n_items) {
        out_items[(size_t)i * 64 + l] = v;
        float s2 = wsum64(v * v);
        if (l == 0) normv[i] = s2;
    } else {
        out_final[(size_t)i * 64 + l] = v;
    }
}

// norms for the user half of cat_nodes
__global__ void user_norm_k(const float* __restrict__ user, float* __restrict__ normv,
                            int n_items, int n_usr) {
    int j = blockIdx.x * (blockDim.x >> 6) + (threadIdx.x >> 6);
    if (j >= n_usr) return;
    int l = threadIdx.x & 63;
    float c = user[(size_t)j * 64 + l];
    float s = wsum64(c * c);
    if (l == 0) normv[n_items + j] = s;
}

// ---------------- CF path ----------------

// iu scatter (no atomics): slot = base_u[d-n_items] + rank_iu[e]
__global__ void iu_scat_k(const int* __restrict__ srcA, const int* __restrict__ dstA,
                          const int* __restrict__ base, const int* __restrict__ rankv,
                          int* __restrict__ payload,
                          int n_items, int N, int nE) {
    int e = blockIdx.x * blockDim.x + threadIdx.x;
    if (e >= nE) return;
    int d = dstA[e];
    if (d < n_items || d >= N) return;
    payload[base[d - n_items] + rankv[e]] = srcA[e];
}

// ui scatter (no atomics): payload = {src, 1/(norm[src]+1e-6)}
__global__ void ui_scat_k(const int* __restrict__ srcA, const int* __restrict__ dstA,
                          const float* __restrict__ normv,
                          const int* __restrict__ base, const int* __restrict__ rankv,
                          float2* __restrict__ payload,
                          int n_items, int nE) {
    int e = blockIdx.x * blockDim.x + threadIdx.x;
    if (e >= nE) return;
    int d = dstA[e];
    if (d >= n_items) return;
    int s = srcA[e];
    payload[base[d] + rankv[e]] = make_float2(__int_as_float(s), frcp(normv[s] + 1e-6f));
}

// wave-per-user gather, 8x unrolled: out_u = (sum cat[src]) / deg
__global__ void iu_gather_k(const float* __restrict__ items, const float* __restrict__ user,
                            const int* __restrict__ deg, const int* __restrict__ base,
                            const int* __restrict__ payload,
                            float* __restrict__ out_u, int n_items, int n) {
    int i = blockIdx.x * (blockDim.x >> 6) + (threadIdx.x >> 6);
    if (i >= n) return;
    int l = threadIdx.x & 63;
    int b = base[i], dg = deg[i];
    float acc = 0.f;
    int q = 0;
    for (; q + 8 <= dg; q += 8) {
        float vs[8];
#pragma unroll
        for (int j = 0; j < 8; ++j) {
            int s0 = payload[b + q + j];
            vs[j] = (s0 < n_items) ? items[(size_t)s0 * 64 + l]
                                   : user[(size_t)(s0 - n_items) * 64 + l];
        }
#pragma unroll
        for (int j = 0; j < 8; ++j) acc += vs[j];
    }
    for (; q < dg; ++q) {
        int s0 = payload[b + q];
        acc += (s0 < n_items) ? items[(size_t)s0 * 64 + l]
                              : user[(size_t)(s0 - n_items) * 64 + l];
    }
    out_u[(size_t)i * 64 + l] = acc * frcp(fmaxf((float)dg, 1.f));
}

// wave-per-item gather, 8x unrolled: icf = norm[i]*(sum f_e*cat[src_e])/deg
__global__ void ui_gather_k(const float* __restrict__ items, const float* __restrict__ user,
                            const float* __restrict__ normv,
                            const int* __restrict__ deg, const int* __restrict__ base,
                            const float2* __restrict__ payload,
                            float* __restrict__ icf, int n_items, int n) {
    int i = blockIdx.x * (blockDim.x >> 6) + (threadIdx.x >> 6);
    if (i >= n) return;
    int l = threadIdx.x & 63;
    int b = base[i], dg = deg[i];
    float acc = 0.f;
    int q = 0;
    for (; q + 8 <= dg; q += 8) {
        float2 ps[8];
        float vs[8];
#pragma unroll
        for (int j = 0; j < 8; ++j) ps[j] = payload[b + q + j];
#pragma unroll
        for (int j = 0; j < 8; ++j) {
            int s0 = __float_as_int(ps[j].x);
            vs[j] = (s0 < n_items) ? items[(size_t)s0 * 64 + l]
                                   : user[(size_t)(s0 - n_items) * 64 + l];
        }
#pragma unroll
        for (int j = 0; j < 8; ++j) acc += ps[j].y * vs[j];
    }
    for (; q < dg; ++q) {
        float2 p0 = payload[b + q];
        int s0 = __float_as_int(p0.x);
        acc += p0.y * ((s0 < n_items) ? items[(size_t)s0 * 64 + l]
                                      : user[(size_t)(s0 - n_items) * 64 + l]);
    }
    icf[(size_t)i * 64 + l] = normv[i] * acc * frcp(fmaxf((float)dg, 1.f));
}

// MFMA gate+fusion: acc = [oi|cf] @ [W1;W2]^T (bf16), out = g*oi + (1-g)*cf.
__global__ __launch_bounds__(256) void fusion_mfma_k(const float* __restrict__ items,
                          const float* __restrict__ icf,
                          const float* __restrict__ W1, const float* __restrict__ W2,
                          float* __restrict__ outf, int n_items) {
    int lane = threadIdx.x & 63;
    int row0 = blockIdx.x * 64 + (threadIdx.x >> 6) * 16;
    int r = lane & 15, g = lane >> 4;

    int arow = row0 + r;
    size_t rbase = (size_t)(arow < n_items ? arow : 0) * 64;

    bf16x8 afrag[4];
#pragma unroll
    for (int s = 0; s < 4; ++s) {
        int kb = s * 32 + g * 8;
        const float* p = (kb < 64) ? (items + rbase + kb) : (icf + rbase + kb - 64);
        afrag[s] = pack8(p);
    }

    bf16x8 bfrag[4][4];
#pragma unroll
    for (int c = 0; c < 4; ++c) {
        int col = c * 16 + r;
#pragma unroll
        for (int s = 0; s < 4; ++s) {
            int kb = s * 32 + g * 8;
            const float* p = (kb < 64) ? (W1 + col * 64 + kb) : (W2 + col * 64 + kb - 64);
            bfrag[c][s] = pack8(p);
        }
    }

    f32x4 acc[4] = {{0.f,0.f,0.f,0.f},{0.f,0.f,0.f,0.f},
                    {0.f,0.f,0.f,0.f},{0.f,0.f,0.f,0.f}};
#pragma unroll
    for (int s = 0; s < 4; ++s)
#pragma unroll
        for (int c = 0; c < 4; ++c)
            acc[c] = __builtin_amdgcn_mfma_f32_16x16x32_bf16(afrag[s], bfrag[c][s],
                                                             acc[c], 0, 0, 0);

#pragma unroll
    for (int c = 0; c < 4; ++c) {
        int col = c * 16 + r;
#pragma unroll
        for (int q = 0; q < 4; ++q) {
            int orow = row0 + g * 4 + q;
            if (orow < n_items) {
                size_t off = (size_t)orow * 64 + col;
                float oi = items[off], cf = icf[off];
                float gate = frcp(1.f + __expf(-acc[c][q]));
                outf[off] = gate * oi + (1.f - gate) * cf;
            }
        }
    }
}

extern "C" void kernel_launch(void* const* d_in, const int* in_sizes, int n_in,
                              void* d_out, int out_size, void* d_ws, size_t ws_size,
                              hipStream_t stream) {
    const float* ent    = (const float*)d_in[0];
    const float* usr    = (const float*)d_in[1];
    const float* rel    = (const float*)d_in[2];
    const float* W1     = (const float*)d_in[3];
    const float* W2     = (const float*)d_in[4];
    const int*   kg_src = (const int*)d_in[5];
    const int*   kg_dst = (const int*)d_in[6];
    const int*   kg_typ = (const int*)d_in[7];
    const int*   iu_src = (const int*)d_in[8];
    const int*   iu_dst = (const int*)d_in[9];
    const int*   ui_src = (const int*)d_in[10];
    const int*   ui_dst = (const int*)d_in[11];

    const int n_ent   = in_sizes[0] / 64;
    const int n_usr   = in_sizes[1] / 64;
    const int E_kg    = in_sizes[5];
    const int E_iu    = in_sizes[8];
    const int E_ui    = in_sizes[10];
    const int n_items = (out_size - in_sizes[0] - in_sizes[1]) / 64;
    const int N       = n_items + n_usr;

    float* out_final = (float*)d_out;                        // (n_ent,64)
    float* out_u     = out_final + (size_t)n_ent * 64;       // (n_usr,64)
    float* out_items = out_u + (size_t)n_usr * 64;           // (n_items,64)

    // rank arrays live in the out_u chunk (12.8MB >= 8MB), consumed by
    // rec_scat/iu_scat/ui_scat, all BEFORE iu_gather_k writes out_u.
    int* rank_kg = (int*)out_u;
    int* rank_iu = rank_kg + E_kg;
    int* rank_ui = rank_iu + E_iu;

    float* ws = (float*)d_ws;
    size_t o = 0;
    // --- contiguous histogram block (single memset) ---
    int*   deg_e = (int*)(ws + o);  o += n_ent;
    int*   gt_e  = (int*)(ws + o);  o += 1;
    int*   deg_u = (int*)(ws + o);  o += n_usr;
    int*   gt_u  = (int*)(ws + o);  o += 1;
    int*   deg_i = (int*)(ws + o);  o += n_items;
    int*   gt_i  = (int*)(ws + o);  o += 1;
    size_t hist_len = ((size_t)(n_ent + n_usr + n_items) + 3) * sizeof(int);
    // --- bases (written by alloc, no zeroing) ---
    int*   base_e = (int*)(ws + o); o += n_ent;
    int*   base_u = (int*)(ws + o); o += n_usr;
    int*   base_i = (int*)(ws + o); o += n_items;
    o = (o + 3) & ~(size_t)3;                      // 16B align
    float4* pay_kg = (float4*)(ws + o); o += (size_t)E_kg * 4;
    int2*   rec_kg = (int2*)(ws + o);   o += (size_t)E_kg * 2;
    int*    pay_iu = (int*)(ws + o);    o += E_iu;
    o = (o + 1) & ~(size_t)1;                      // 8B align
    float2* pay_ui = (float2*)(ws + o); o += (size_t)E_ui * 2;
    float* normv = ws + o;          o += N;
    o = (o + 3) & ~(size_t)3;                      // 16B align
    float* icf   = ws + o;          o += (size_t)n_items * 64;

    hipMemsetAsync(deg_e, 0, hist_len, stream);

    // hist+rank (one pass), scan-based base allocation
    long tot_hist = (long)E_kg + E_iu + E_ui;
    rank3_k<<<(int)((tot_hist + 2047) / 2048), 256, 0, stream>>>(
        kg_src, iu_dst, ui_dst, deg_e, deg_u, deg_i,
        rank_kg, rank_iu, rank_ui, E_kg, E_iu, E_ui, n_items, N);
    int Be = (n_ent + 255) / 256, Bu = (n_usr + 255) / 256, Bi = (n_items + 255) / 256;
    alloc3_k<<<Be + Bu + Bi, 256, 0, stream>>>(deg_e, deg_u, deg_i,
                                               base_e, base_u, base_i,
                                               gt_e, gt_u, gt_i,
                                               n_ent, n_usr, n_items, Be, Bu);

    // KG compute (CSR-ordered edge pass)
    rec_scat_k<<<(E_kg + 255) / 256, 256, 0, stream>>>(kg_src, kg_dst, kg_typ,
                                                       base_e, rank_kg, rec_kg, E_kg);
    kg_edge_fused_k<<<(E_kg + 63) / 64, 256, 0, stream>>>(ent, rel, rec_kg,
                                                          pay_kg, E_kg);
    kg_gather_k<<<(n_ent + 3) / 4, 256, 0, stream>>>(ent, rel, deg_e, base_e, pay_kg,
                                                     out_final, out_items, normv,
                                                     n_items, n_ent);
    user_norm_k<<<(n_usr + 3) / 4, 256, 0, stream>>>(usr, normv, n_items, n_usr);

    // CF scatters (atomic-free), then gathers (iu_gather overwrites out_u AFTER
    // all rank consumers have run)
    iu_scat_k<<<(E_iu + 255) / 256, 256, 0, stream>>>(iu_src, iu_dst, base_u, rank_iu,
                                                      pay_iu, n_items, N, E_iu);
    ui_scat_k<<<(E_ui + 255) / 256, 256, 0, stream>>>(ui_src, ui_dst, normv, base_i,
                                                      rank_ui, pay_ui, n_items, E_ui);
    iu_gather_k<<<(n_usr + 3) / 4, 256, 0, stream>>>(out_items, usr, deg_u, base_u,
                                                     pay_iu, out_u, n_items, n_usr);
    ui_gather_k<<<(n_items + 3) / 4, 256, 0, stream>>>(out_items, usr, normv, deg_i,
                                                       base_i, pay_ui, icf, n_items,
                                                       n_items);
    fusion_mfma_k<<<(n_items + 63) / 64, 256, 0, stream>>>(out_items, icf, W1, W2,
                                                           out_final, n_items);
}

// Round 13
// 241.785 us; speedup vs baseline: 1.4246x; 1.2831x over previous
//
#include <hip/hip_runtime.h>
#include <cstdint>

#define EPSF 1e-15f
#define MAXN (1.0f - 1e-5f)
#define BSH 9   // 512 slots per bin

typedef __attribute__((ext_vector_type(8))) short bf16x8;
typedef __attribute__((ext_vector_type(4))) float f32x4;

__device__ __forceinline__ float wsum64(float v) {
    v += __shfl_xor(v, 1);
    v += __shfl_xor(v, 2);
    v += __shfl_xor(v, 4);
    v += __shfl_xor(v, 8);
    v += __shfl_xor(v, 16);
    v += __shfl_xor(v, 32);
    return v;
}

__device__ __forceinline__ float dot4(float4 a, float4 b) {
    return a.x * b.x + a.y * b.y + a.z * b.z + a.w * b.w;
}

__device__ __forceinline__ float frcp(float x) {
    return __builtin_amdgcn_rcpf(x);
}

__device__ __forceinline__ float tanh_f(float x) {
    x = fminf(x, 10.f);
    float t = __expf(2.f * x);
    return (t - 1.f) * frcp(t + 1.f);
}

__device__ __forceinline__ float atanh_f(float x) {
    return 0.5f * __logf((1.f + x) * frcp(1.f - x));
}

__device__ __forceinline__ short f2bf(float f) {
    uint32_t b = __float_as_uint(f);
    b = (b + 0x7FFF + ((b >> 16) & 1)) >> 16;
    return (short)b;
}

__device__ __forceinline__ bf16x8 pack8(const float* __restrict__ p) {
    float4 lo = *(const float4*)p;
    float4 hi = *(const float4*)(p + 4);
    bf16x8 r;
    r[0] = f2bf(lo.x); r[1] = f2bf(lo.y); r[2] = f2bf(lo.z); r[3] = f2bf(lo.w);
    r[4] = f2bf(hi.x); r[5] = f2bf(hi.y); r[6] = f2bf(hi.z); r[7] = f2bf(hi.w);
    return r;
}

// ---------------- CSR build: binned counting sort (zero global atomics) ------

// P1: per-block LDS histogram over coarse bins; write block's bin row.
__global__ __launch_bounds__(256) void p1_hist_k(
        const int* __restrict__ kg_src, const int* __restrict__ iu_dst,
        const int* __restrict__ ui_dst, int* __restrict__ H,
        int E_kg, int E_iu, int E_ui, int n_items, int S1, int SU, int nbins) {
    __shared__ int h[512];
    int tid = threadIdx.x;
    h[tid] = 0; h[tid + 256] = 0;
    __syncthreads();
    long tot = (long)E_kg + E_iu + E_ui;
    long b0 = (long)blockIdx.x * 2048 + tid;
#pragma unroll
    for (int j = 0; j < 8; ++j) {
        long t = b0 + (long)j * 256;
        if (t < tot) {
            int slot;
            if (t < E_kg) slot = kg_src[t];
            else if (t < (long)E_kg + E_iu) slot = S1 + iu_dst[t - E_kg] - n_items;
            else slot = S1 + SU + ui_dst[t - E_kg - E_iu];
            atomicAdd(&h[slot >> BSH], 1);
        }
    }
    __syncthreads();
    int* row = H + (size_t)blockIdx.x * nbins;
    if (tid < nbins) row[tid] = h[tid];
    if (tid + 256 < nbins) row[tid + 256] = h[tid + 256];
}

// P2a: per-bin column scan over blocks (in place) -> binTotal.
__global__ __launch_bounds__(256) void p2a_scan_k(int* __restrict__ H,
        int* __restrict__ binTotal, int NBLK, int nbins) {
    int bin = blockIdx.x, tid = threadIdx.x;
    int lane = tid & 63, w = tid >> 6;
    __shared__ int wtot[4];
    int carry = 0;
    for (int c0 = 0; c0 < NBLK; c0 += 256) {
        int idx = c0 + tid;
        int v = (idx < NBLK) ? H[(size_t)idx * nbins + bin] : 0;
        int inc = v;
#pragma unroll
        for (int off = 1; off < 64; off <<= 1) {
            int u = __shfl_up(inc, off);
            if (lane >= off) inc += u;
        }
        if (lane == 63) wtot[w] = inc;
        __syncthreads();
        int woff = 0;
        for (int i = 0; i < w; ++i) woff += wtot[i];
        int ctot = wtot[0] + wtot[1] + wtot[2] + wtot[3];
        if (idx < NBLK) H[(size_t)idx * nbins + bin] = carry + woff + inc - v;
        carry += ctot;
        __syncthreads();
    }
    if (tid == 0) binTotal[bin] = carry;
}

// P2b: exclusive scan of binTotal -> binStart (nbins <= 512).
__global__ __launch_bounds__(512) void p2b_bins_k(const int* __restrict__ binTotal,
        int* __restrict__ binStart, int nbins) {
    int tid = threadIdx.x, lane = tid & 63, w = tid >> 6;
    __shared__ int wtot[8];
    int v = (tid < nbins) ? binTotal[tid] : 0;
    int inc = v;
#pragma unroll
    for (int off = 1; off < 64; off <<= 1) {
        int u = __shfl_up(inc, off);
        if (lane >= off) inc += u;
    }
    if (lane == 63) wtot[w] = inc;
    __syncthreads();
    int woff = 0;
    for (int i = 0; i < w; ++i) woff += wtot[i];
    if (tid < nbins) binStart[tid] = woff + inc - v;
    if (tid == 0) {
        int tot = 0;
        for (int i = 0; i < 8; ++i) tot += wtot[i];
        binStart[nbins] = tot;
    }
}

// P3: scatter records into bin-grouped order via LDS cursors.
__global__ __launch_bounds__(256) void p3_scat_k(
        const int* __restrict__ kg_src, const int* __restrict__ kg_dst,
        const int* __restrict__ kg_typ, const int* __restrict__ iu_src,
        const int* __restrict__ iu_dst, const int* __restrict__ ui_src,
        const int* __restrict__ ui_dst,
        const int* __restrict__ H, const int* __restrict__ binStart,
        int2* __restrict__ recA,
        int E_kg, int E_iu, int E_ui, int n_items, int S1, int SU, int nbins) {
    __shared__ int off[512];
    int tid = threadIdx.x;
    const int* row = H + (size_t)blockIdx.x * nbins;
    if (tid < nbins) off[tid] = binStart[tid] + row[tid];
    if (tid + 256 < nbins) off[tid + 256] = binStart[tid + 256] + row[tid + 256];
    __syncthreads();
    long tot = (long)E_kg + E_iu + E_ui;
    long b0 = (long)blockIdx.x * 2048 + tid;
#pragma unroll
    for (int j = 0; j < 8; ++j) {
        long t = b0 + (long)j * 256;
        if (t < tot) {
            int slot, aux;
            if (t < E_kg) {
                slot = kg_src[t];
                aux = kg_dst[t] | ((kg_typ[t] + 2) << 18);
            } else if (t < (long)E_kg + E_iu) {
                long e = t - E_kg;
                slot = S1 + iu_dst[e] - n_items;
                aux = iu_src[e];
            } else {
                long e = t - E_kg - E_iu;
                slot = S1 + SU + ui_dst[e];
                aux = ui_src[e];
            }
            int pos = atomicAdd(&off[slot >> BSH], 1);
            recA[pos] = make_int2(slot, aux);
        }
    }
}

// P4: per-bin fine sort: LDS hist over 512 slots -> deg/base + final scatter.
__global__ __launch_bounds__(256) void p4_sort_k(
        const int2* __restrict__ recA, const int* __restrict__ binStart,
        int2* __restrict__ recB, int* __restrict__ deg, int* __restrict__ base,
        int nbins) {
    int b = blockIdx.x, tid = threadIdx.x;
    int lane = tid & 63, w = tid >> 6;
    int lo = binStart[b], cnt = binStart[b + 1] - lo;
    __shared__ int h[512];
    __shared__ int pre[512];
    __shared__ int wtot[4];
    h[tid] = 0; h[tid + 256] = 0;
    __syncthreads();
    for (int i = tid; i < cnt; i += 256)
        atomicAdd(&h[recA[lo + i].x & 511], 1);
    __syncthreads();
    // scan chunk 1 (slots 0..255)
    int v1 = h[tid];
    int inc = v1;
#pragma unroll
    for (int off = 1; off < 64; off <<= 1) {
        int u = __shfl_up(inc, off);
        if (lane >= off) inc += u;
    }
    if (lane == 63) wtot[w] = inc;
    __syncthreads();
    int woff = 0;
    for (int i = 0; i < w; ++i) woff += wtot[i];
    int T1 = wtot[0] + wtot[1] + wtot[2] + wtot[3];
    int p1 = woff + inc - v1;
    __syncthreads();
    // scan chunk 2 (slots 256..511)
    int v2 = h[tid + 256];
    inc = v2;
#pragma unroll
    for (int off = 1; off < 64; off <<= 1) {
        int u = __shfl_up(inc, off);
        if (lane >= off) inc += u;
    }
    if (lane == 63) wtot[w] = inc;
    __syncthreads();
    woff = 0;
    for (int i = 0; i < w; ++i) woff += wtot[i];
    int p2 = T1 + woff + inc - v2;
    pre[tid] = p1; pre[tid + 256] = p2;
    int slot0 = (b << BSH) + tid;
    deg[slot0] = v1;       base[slot0] = lo + p1;
    deg[slot0 + 256] = v2; base[slot0 + 256] = lo + p2;
    __syncthreads();
    for (int i = tid; i < cnt; i += 256) {
        int2 r = recA[lo + i];
        int p = atomicAdd(&pre[r.x & 511], 1);
        recB[lo + p] = r;
    }
}

// ---------------- KG path ----------------

// Merged dots+chain in CSR (slot) order; 4 lanes/edge coalesced reads,
// 2-step shfl reduce, fast-math chain; payload write coalesced at slot.
__global__ __launch_bounds__(256) void kg_edge_fused_k(const float* __restrict__ ent,
                          const float* __restrict__ rel,
                          const int2* __restrict__ rec,
                          float4* __restrict__ payload,
                          int nE) {
    int w = blockIdx.x * 4 + (threadIdx.x >> 6);
    int l = threadIdx.x & 63;
    int slot = w * 16 + (l >> 2);
    if (slot >= nE) return;
    int j0 = l & 3;
    int2 rc = rec[slot];
    int s = rc.x, d = rc.y & 0x3FFFF, ty = rc.y >> 18;
    const float4* pu = (const float4*)(ent + (size_t)s * 64);
    const float4* pv = (const float4*)(ent + (size_t)d * 64);
    const float4* pr = (const float4*)(rel + (size_t)ty * 64);

    float uu = 0.f, vv = 0.f, rr = 0.f, uv = 0.f, ur = 0.f, vr = 0.f;
#pragma unroll
    for (int i = 0; i < 4; ++i) {
        float4 a = pu[4 * i + j0], b = pv[4 * i + j0], c = pr[4 * i + j0];
        uu += dot4(a, a); vv += dot4(b, b); rr += dot4(c, c);
        uv += dot4(a, b); ur += dot4(a, c); vr += dot4(b, c);
    }
#pragma unroll
    for (int m = 1; m < 4; m <<= 1) {
        uu += __shfl_xor(uu, m);
        vv += __shfl_xor(vv, m);
        rr += __shfl_xor(rr, m);
        uv += __shfl_xor(uv, m);
        ur += __shfl_xor(ur, m);
        vr += __shfl_xor(vr, m);
    }

    float n0 = sqrtf(fmaxf(uu, EPSF));
    float cp = tanh_f(n0) * frcp(n0);
    float p2 = cp * cp * uu;
    float om_p2 = 1.f - p2;
    float lam = 2.f * frcp(fmaxf(om_p2, EPSF));

    float nv = sqrtf(fmaxf(vv, EPSF));
    float cd = tanh_f(0.5f * lam * nv) * frcp(nv);
    float wd2 = cd * cd * vv;
    float pwd = cp * cd * uv;
    float iDd = frcp(fmaxf(1.f + 2.f * pwd + p2 * wd2, EPSF));
    float a1 = (1.f + 2.f * pwd + wd2) * cp * iDd;
    float b1 = om_p2 * cd * iDd;

    float nr = sqrtf(fmaxf(rr, EPSF));
    float cr = tanh_f(0.5f * lam * nr) * frcp(nr);
    float wr2 = cr * cr * rr;
    float pwr = cp * cr * ur;
    float iDr = frcp(fmaxf(1.f + 2.f * pwr + p2 * wr2, EPSF));
    float a2 = (1.f + 2.f * pwr + wr2) * cp * iDr;
    float c2 = om_p2 * cr * iDr;

    float x2 = a1 * a1 * uu + 2.f * a1 * b1 * uv + b1 * b1 * vv;
    float y2 = a2 * a2 * uu + 2.f * a2 * c2 * ur + c2 * c2 * rr;
    float xy = a1 * a2 * uu + a1 * c2 * ur + b1 * a2 * uv + b1 * c2 * vr;
    float iden = frcp(fmaxf(1.f + 2.f * xy + x2 * y2, EPSF));
    float E = (1.f + 2.f * xy + y2) * iden;
    float F = (1.f - x2) * iden;
    float zu = E * a1 + F * a2;
    float zv = E * b1;
    float zr = F * c2;

    float z2 = zu * zu * uu + zv * zv * vv + zr * zr * rr
             + 2.f * (zu * zv * uv + zu * zr * ur + zv * zr * vr);
    float nz = sqrtf(fmaxf(z2, EPSF));
    if (nz > MAXN) {
        float sc = MAXN * frcp(nz);
        zu *= sc; zv *= sc; zr *= sc;
        z2 *= sc * sc;
    }

    float mxy = -cp * (zu * uu + zv * uv + zr * ur);
    float idenl = frcp(fmaxf(1.f + 2.f * mxy + p2 * z2, EPSF));
    float G = (1.f + 2.f * mxy + z2) * idenl;
    float H = om_p2 * idenl;
    float su = -G * cp + H * zu;
    float sv = H * zv;
    float sr = H * zr;

    float ns2 = su * su * uu + sv * sv * vv + sr * sr * rr
              + 2.f * (su * sv * uv + su * sr * ur + sv * sr * vr);
    float ns = sqrtf(fmaxf(ns2, EPSF));
    float k = fmaxf(om_p2, EPSF) * atanh_f(fminf(ns, MAXN)) * frcp(ns);

    if (j0 == 0) {
        payload[slot] = make_float4(k * sv, k * sr, k * su, __int_as_float(rc.y));
    }
}

// Wave-per-entity CSR gather, 4x unrolled; also emits item-row norms.
__global__ void kg_gather_k(const float* __restrict__ ent,
                            const float* __restrict__ rel,
                            const int* __restrict__ deg,
                            const int* __restrict__ base,
                            const float4* __restrict__ payload,
                            float* __restrict__ out_final,
                            float* __restrict__ out_items,
                            float* __restrict__ normv,
                            int n_items, int n) {
    int i = blockIdx.x * (blockDim.x >> 6) + (threadIdx.x >> 6);
    if (i >= n) return;
    int l = threadIdx.x & 63;
    int b = base[i], dg = deg[i];
    float acc = 0.f, as = 0.f;
    int q = 0;
    for (; q + 4 <= dg; q += 4) {
        float4 p0 = payload[b + q];
        float4 p1 = payload[b + q + 1];
        float4 p2 = payload[b + q + 2];
        float4 p3 = payload[b + q + 3];
        int w0 = __float_as_int(p0.w), w1 = __float_as_int(p1.w);
        int w2 = __float_as_int(p2.w), w3 = __float_as_int(p3.w);
        float v0 = ent[(size_t)(w0 & 0x3FFFF) * 64 + l];
        float r0 = rel[(size_t)(w0 >> 18) * 64 + l];
        float v1 = ent[(size_t)(w1 & 0x3FFFF) * 64 + l];
        float r1 = rel[(size_t)(w1 >> 18) * 64 + l];
        float v2 = ent[(size_t)(w2 & 0x3FFFF) * 64 + l];
        float r2 = rel[(size_t)(w2 >> 18) * 64 + l];
        float v3 = ent[(size_t)(w3 & 0x3FFFF) * 64 + l];
        float r3 = rel[(size_t)(w3 >> 18) * 64 + l];
        acc += p0.x * v0 + p0.y * r0 + p1.x * v1 + p1.y * r1;
        acc += p2.x * v2 + p2.y * r2 + p3.x * v3 + p3.y * r3;
        as += (p0.z + p1.z) + (p2.z + p3.z);
    }
    for (; q < dg; ++q) {
        float4 p = payload[b + q];
        int w = __float_as_int(p.w);
        acc += p.x * ent[(size_t)(w & 0x3FFFF) * 64 + l]
             + p.y * rel[(size_t)(w >> 18) * 64 + l];
        as += p.z;
    }
    float v = (acc + as * ent[(size_t)i * 64 + l]) * frcp(fmaxf((float)dg, 1.f));
    if (i < n_items) {
        out_items[(size_t)i * 64 + l] = v;
        float s2 = wsum64(v * v);
        if (l == 0) normv[i] = s2;
    } else {
        out_final[(size_t)i * 64 + l] = v;
    }
}

// norms for the user half of cat_nodes
__global__ void user_norm_k(const float* __restrict__ user, float* __restrict__ normv,
                            int n_items, int n_usr) {
    int j = blockIdx.x * (blockDim.x >> 6) + (threadIdx.x >> 6);
    if (j >= n_usr) return;
    int l = threadIdx.x & 63;
    float c = user[(size_t)j * 64 + l];
    float s = wsum64(c * c);
    if (l == 0) normv[n_items + j] = s;
}

// ---------------- CF path ----------------

// wave-per-user gather, 8x unrolled: out_u = (sum cat[src]) / deg
__global__ void iu_gather_k(const float* __restrict__ items, const float* __restrict__ user,
                            const int* __restrict__ deg, const int* __restrict__ base,
                            const int2* __restrict__ rec,
                            float* __restrict__ out_u, int n_items, int n, int SOFF) {
    int i = blockIdx.x * (blockDim.x >> 6) + (threadIdx.x >> 6);
    if (i >= n) return;
    int l = threadIdx.x & 63;
    int b = base[SOFF + i], dg = deg[SOFF + i];
    float acc = 0.f;
    int q = 0;
    for (; q + 8 <= dg; q += 8) {
        float vs[8];
#pragma unroll
        for (int j = 0; j < 8; ++j) {
            int s0 = rec[b + q + j].y;
            vs[j] = (s0 < n_items) ? items[(size_t)s0 * 64 + l]
                                   : user[(size_t)(s0 - n_items) * 64 + l];
        }
#pragma unroll
        for (int j = 0; j < 8; ++j) acc += vs[j];
    }
    for (; q < dg; ++q) {
        int s0 = rec[b + q].y;
        acc += (s0 < n_items) ? items[(size_t)s0 * 64 + l]
                              : user[(size_t)(s0 - n_items) * 64 + l];
    }
    out_u[(size_t)i * 64 + l] = acc * frcp(fmaxf((float)dg, 1.f));
}

// wave-per-item gather, 8x unrolled: icf = norm[i]*(sum cat[s]/(norm[s]+1e-6))/deg
__global__ void ui_gather_k(const float* __restrict__ items, const float* __restrict__ user,
                            const float* __restrict__ normv,
                            const int* __restrict__ deg, const int* __restrict__ base,
                            const int2* __restrict__ rec,
                            float* __restrict__ icf, int n_items, int n, int SOFF) {
    int i = blockIdx.x * (blockDim.x >> 6) + (threadIdx.x >> 6);
    if (i >= n) return;
    int l = threadIdx.x & 63;
    int b = base[SOFF + i], dg = deg[SOFF + i];
    float acc = 0.f;
    int q = 0;
    for (; q + 8 <= dg; q += 8) {
        int ss[8]; float fs[8]; float vs[8];
#pragma unroll
        for (int j = 0; j < 8; ++j) ss[j] = rec[b + q + j].y;
#pragma unroll
        for (int j = 0; j < 8; ++j) fs[j] = frcp(normv[ss[j]] + 1e-6f);
#pragma unroll
        for (int j = 0; j < 8; ++j) {
            int s0 = ss[j];
            vs[j] = (s0 < n_items) ? items[(size_t)s0 * 64 + l]
                                   : user[(size_t)(s0 - n_items) * 64 + l];
        }
#pragma unroll
        for (int j = 0; j < 8; ++j) acc += fs[j] * vs[j];
    }
    for (; q < dg; ++q) {
        int s0 = rec[b + q].y;
        float f = frcp(normv[s0] + 1e-6f);
        acc += f * ((s0 < n_items) ? items[(size_t)s0 * 64 + l]
                                   : user[(size_t)(s0 - n_items) * 64 + l]);
    }
    icf[(size_t)i * 64 + l] = normv[i] * acc * frcp(fmaxf((float)dg, 1.f));
}

// MFMA gate+fusion: acc = [oi|cf] @ [W1;W2]^T (bf16), out = g*oi + (1-g)*cf.
__global__ __launch_bounds__(256) void fusion_mfma_k(const float* __restrict__ items,
                          const float* __restrict__ icf,
                          const float* __restrict__ W1, const float* __restrict__ W2,
                          float* __restrict__ outf, int n_items) {
    int lane = threadIdx.x & 63;
    int row0 = blockIdx.x * 64 + (threadIdx.x >> 6) * 16;
    int r = lane & 15, g = lane >> 4;

    int arow = row0 + r;
    size_t rbase = (size_t)(arow < n_items ? arow : 0) * 64;

    bf16x8 afrag[4];
#pragma unroll
    for (int s = 0; s < 4; ++s) {
        int kb = s * 32 + g * 8;
        const float* p = (kb < 64) ? (items + rbase + kb) : (icf + rbase + kb - 64);
        afrag[s] = pack8(p);
    }

    bf16x8 bfrag[4][4];
#pragma unroll
    for (int c = 0; c < 4; ++c) {
        int col = c * 16 + r;
#pragma unroll
        for (int s = 0; s < 4; ++s) {
            int kb = s * 32 + g * 8;
            const float* p = (kb < 64) ? (W1 + col * 64 + kb) : (W2 + col * 64 + kb - 64);
            bfrag[c][s] = pack8(p);
        }
    }

    f32x4 acc[4] = {{0.f,0.f,0.f,0.f},{0.f,0.f,0.f,0.f},
                    {0.f,0.f,0.f,0.f},{0.f,0.f,0.f,0.f}};
#pragma unroll
    for (int s = 0; s < 4; ++s)
#pragma unroll
        for (int c = 0; c < 4; ++c)
            acc[c] = __builtin_amdgcn_mfma_f32_16x16x32_bf16(afrag[s], bfrag[c][s],
                                                             acc[c], 0, 0, 0);

#pragma unroll
    for (int c = 0; c < 4; ++c) {
        int col = c * 16 + r;
#pragma unroll
        for (int q = 0; q < 4; ++q) {
            int orow = row0 + g * 4 + q;
            if (orow < n_items) {
                size_t off = (size_t)orow * 64 + col;
                float oi = items[off], cf = icf[off];
                float gate = frcp(1.f + __expf(-acc[c][q]));
                outf[off] = gate * oi + (1.f - gate) * cf;
            }
        }
    }
}

extern "C" void kernel_launch(void* const* d_in, const int* in_sizes, int n_in,
                              void* d_out, int out_size, void* d_ws, size_t ws_size,
                              hipStream_t stream) {
    const float* ent    = (const float*)d_in[0];
    const float* usr    = (const float*)d_in[1];
    const float* rel    = (const float*)d_in[2];
    const float* W1     = (const float*)d_in[3];
    const float* W2     = (const float*)d_in[4];
    const int*   kg_src = (const int*)d_in[5];
    const int*   kg_dst = (const int*)d_in[6];
    const int*   kg_typ = (const int*)d_in[7];
    const int*   iu_src = (const int*)d_in[8];
    const int*   iu_dst = (const int*)d_in[9];
    const int*   ui_src = (const int*)d_in[10];
    const int*   ui_dst = (const int*)d_in[11];

    const int n_ent   = in_sizes[0] / 64;
    const int n_usr   = in_sizes[1] / 64;
    const int E_kg    = in_sizes[5];
    const int E_iu    = in_sizes[8];
    const int E_ui    = in_sizes[10];
    const int n_items = (out_size - in_sizes[0] - in_sizes[1]) / 64;
    const int N       = n_items + n_usr;

    // unified slot space: [ent | user | item], each 512-aligned
    const int S1 = ((n_ent + 511) / 512) * 512;
    const int SU = ((n_usr + 511) / 512) * 512;
    const int SI = ((n_items + 511) / 512) * 512;
    const int S3 = S1 + SU + SI;
    const int nbins = S3 >> BSH;
    const long tot = (long)E_kg + E_iu + E_ui;
    const int NBLK = (int)((tot + 2047) / 2048);

    float* out_final = (float*)d_out;                        // (n_ent,64)
    float* out_u     = out_final + (size_t)n_ent * 64;       // (n_usr,64)
    float* out_items = out_u + (size_t)n_usr * 64;           // (n_items,64)

    // d_out tail scratch (dead before kg/iu gathers write these chunks):
    // recA = bin-grouped intermediate records (tot*8B), H after it.
    int2* recA = (int2*)out_u;                               // tot * 8B
    int*  H    = (int*)(recA + tot);                         // NBLK*nbins*4B

    float* ws = (float*)d_ws;
    size_t o = 0;
    int* binTotal = (int*)(ws + o); o += nbins;
    int* binStart = (int*)(ws + o); o += nbins + 1;
    int* deg      = (int*)(ws + o); o += S3;
    int* basep    = (int*)(ws + o); o += S3;
    o = (o + 3) & ~(size_t)3;                      // 16B align
    int2* recB    = (int2*)(ws + o); o += (size_t)tot * 2;
    float4* pay_kg = (float4*)(ws + o); o += (size_t)E_kg * 4;
    float* icf    = (float*)pay_kg;   // alias: pay_kg dead after kg_gather
    float* normv  = ws + o; o += N;

    // CSR build (all LDS atomics; no memsets - every buffer fully written)
    p1_hist_k<<<NBLK, 256, 0, stream>>>(kg_src, iu_dst, ui_dst, H,
                                        E_kg, E_iu, E_ui, n_items, S1, SU, nbins);
    p2a_scan_k<<<nbins, 256, 0, stream>>>(H, binTotal, NBLK, nbins);
    p2b_bins_k<<<1, 512, 0, stream>>>(binTotal, binStart, nbins);
    p3_scat_k<<<NBLK, 256, 0, stream>>>(kg_src, kg_dst, kg_typ, iu_src, iu_dst,
                                        ui_src, ui_dst, H, binStart, recA,
                                        E_kg, E_iu, E_ui, n_items, S1, SU, nbins);
    p4_sort_k<<<nbins, 256, 0, stream>>>(recA, binStart, recB, deg, basep, nbins);

    // KG compute (CSR-ordered edge pass; kg records = recB[0..E_kg))
    kg_edge_fused_k<<<(E_kg + 63) / 64, 256, 0, stream>>>(ent, rel, recB,
                                                          pay_kg, E_kg);
    kg_gather_k<<<(n_ent + 3) / 4, 256, 0, stream>>>(ent, rel, deg, basep, pay_kg,
                                                     out_final, out_items, normv,
                                                     n_items, n_ent);
    user_norm_k<<<(n_usr + 3) / 4, 256, 0, stream>>>(usr, normv, n_items, n_usr);

    // CF gathers (direct output writes; recA/H in d_out are dead by now)
    iu_gather_k<<<(n_usr + 3) / 4, 256, 0, stream>>>(out_items, usr, deg, basep,
                                                     recB, out_u, n_items, n_usr, S1);
    ui_gather_k<<<(n_items + 3) / 4, 256, 0, stream>>>(out_items, usr, normv, deg,
                                                       basep, recB, icf, n_items,
                                                       n_items, S1 + SU);
    fusion_mfma_k<<<(n_items + 63) / 64, 256, 0, stream>>>(out_items, icf, W1, W2,
                                                           out_final, n_items);
}

// Round 14
// 234.462 us; speedup vs baseline: 1.4690x; 1.0312x over previous
//
#include <hip/hip_runtime.h>
#include <cstdint>

#define EPSF 1e-15f
#define MAXN (1.0f - 1e-5f)
#define BSH 9   // 512 slots per bin

typedef __attribute__((ext_vector_type(8))) short bf16x8;
typedef __attribute__((ext_vector_type(4))) float f32x4;

__device__ __forceinline__ float wsum64(float v) {
    v += __shfl_xor(v, 1);
    v += __shfl_xor(v, 2);
    v += __shfl_xor(v, 4);
    v += __shfl_xor(v, 8);
    v += __shfl_xor(v, 16);
    v += __shfl_xor(v, 32);
    return v;
}

__device__ __forceinline__ float dot4(float4 a, float4 b) {
    return a.x * b.x + a.y * b.y + a.z * b.z + a.w * b.w;
}

__device__ __forceinline__ float frcp(float x) {
    return __builtin_amdgcn_rcpf(x);
}

__device__ __forceinline__ float tanh_f(float x) {
    x = fminf(x, 10.f);
    float t = __expf(2.f * x);
    return (t - 1.f) * frcp(t + 1.f);
}

__device__ __forceinline__ float atanh_f(float x) {
    return 0.5f * __logf((1.f + x) * frcp(1.f - x));
}

__device__ __forceinline__ short f2bf(float f) {
    uint32_t b = __float_as_uint(f);
    b = (b + 0x7FFF + ((b >> 16) & 1)) >> 16;
    return (short)b;
}

__device__ __forceinline__ bf16x8 pack8(const float* __restrict__ p) {
    float4 lo = *(const float4*)p;
    float4 hi = *(const float4*)(p + 4);
    bf16x8 r;
    r[0] = f2bf(lo.x); r[1] = f2bf(lo.y); r[2] = f2bf(lo.z); r[3] = f2bf(lo.w);
    r[4] = f2bf(hi.x); r[5] = f2bf(hi.y); r[6] = f2bf(hi.z); r[7] = f2bf(hi.w);
    return r;
}

// ---------------- CSR build: binned counting sort (zero global atomics) ------

// P1: per-block LDS histogram over coarse bins; write block's bin row.
__global__ __launch_bounds__(256) void p1_hist_k(
        const int* __restrict__ kg_src, const int* __restrict__ iu_dst,
        const int* __restrict__ ui_dst, int* __restrict__ H,
        int E_kg, int E_iu, int E_ui, int n_items, int S1, int SU, int nbins) {
    __shared__ int h[512];
    int tid = threadIdx.x;
    h[tid] = 0; h[tid + 256] = 0;
    __syncthreads();
    long tot = (long)E_kg + E_iu + E_ui;
    long b0 = (long)blockIdx.x * 2048 + tid;
#pragma unroll
    for (int j = 0; j < 8; ++j) {
        long t = b0 + (long)j * 256;
        if (t < tot) {
            int slot;
            if (t < E_kg) slot = kg_src[t];
            else if (t < (long)E_kg + E_iu) slot = S1 + iu_dst[t - E_kg] - n_items;
            else slot = S1 + SU + ui_dst[t - E_kg - E_iu];
            atomicAdd(&h[slot >> BSH], 1);
        }
    }
    __syncthreads();
    int* row = H + (size_t)blockIdx.x * nbins;
    if (tid < nbins) row[tid] = h[tid];
    if (tid + 256 < nbins) row[tid + 256] = h[tid + 256];
}

// P2a: per-bin column scan over blocks (in place) -> binTotal.
__global__ __launch_bounds__(256) void p2a_scan_k(int* __restrict__ H,
        int* __restrict__ binTotal, int NBLK, int nbins) {
    int bin = blockIdx.x, tid = threadIdx.x;
    int lane = tid & 63, w = tid >> 6;
    __shared__ int wtot[4];
    int carry = 0;
    for (int c0 = 0; c0 < NBLK; c0 += 256) {
        int idx = c0 + tid;
        int v = (idx < NBLK) ? H[(size_t)idx * nbins + bin] : 0;
        int inc = v;
#pragma unroll
        for (int off = 1; off < 64; off <<= 1) {
            int u = __shfl_up(inc, off);
            if (lane >= off) inc += u;
        }
        if (lane == 63) wtot[w] = inc;
        __syncthreads();
        int woff = 0;
        for (int i = 0; i < w; ++i) woff += wtot[i];
        int ctot = wtot[0] + wtot[1] + wtot[2] + wtot[3];
        if (idx < NBLK) H[(size_t)idx * nbins + bin] = carry + woff + inc - v;
        carry += ctot;
        __syncthreads();
    }
    if (tid == 0) binTotal[bin] = carry;
}

// P2b: exclusive scan of binTotal -> binStart (nbins <= 512).
__global__ __launch_bounds__(512) void p2b_bins_k(const int* __restrict__ binTotal,
        int* __restrict__ binStart, int nbins) {
    int tid = threadIdx.x, lane = tid & 63, w = tid >> 6;
    __shared__ int wtot[8];
    int v = (tid < nbins) ? binTotal[tid] : 0;
    int inc = v;
#pragma unroll
    for (int off = 1; off < 64; off <<= 1) {
        int u = __shfl_up(inc, off);
        if (lane >= off) inc += u;
    }
    if (lane == 63) wtot[w] = inc;
    __syncthreads();
    int woff = 0;
    for (int i = 0; i < w; ++i) woff += wtot[i];
    if (tid < nbins) binStart[tid] = woff + inc - v;
    if (tid == 0) {
        int tot = 0;
        for (int i = 0; i < 8; ++i) tot += wtot[i];
        binStart[nbins] = tot;
    }
}

// P3: scatter records into bin-grouped order via LDS cursors.
__global__ __launch_bounds__(256) void p3_scat_k(
        const int* __restrict__ kg_src, const int* __restrict__ kg_dst,
        const int* __restrict__ kg_typ, const int* __restrict__ iu_src,
        const int* __restrict__ iu_dst, const int* __restrict__ ui_src,
        const int* __restrict__ ui_dst,
        const int* __restrict__ H, const int* __restrict__ binStart,
        int2* __restrict__ recA,
        int E_kg, int E_iu, int E_ui, int n_items, int S1, int SU, int nbins) {
    __shared__ int off[512];
    int tid = threadIdx.x;
    const int* row = H + (size_t)blockIdx.x * nbins;
    if (tid < nbins) off[tid] = binStart[tid] + row[tid];
    if (tid + 256 < nbins) off[tid + 256] = binStart[tid + 256] + row[tid + 256];
    __syncthreads();
    long tot = (long)E_kg + E_iu + E_ui;
    long b0 = (long)blockIdx.x * 2048 + tid;
#pragma unroll
    for (int j = 0; j < 8; ++j) {
        long t = b0 + (long)j * 256;
        if (t < tot) {
            int slot, aux;
            if (t < E_kg) {
                slot = kg_src[t];
                aux = kg_dst[t] | ((kg_typ[t] + 2) << 18);
            } else if (t < (long)E_kg + E_iu) {
                long e = t - E_kg;
                slot = S1 + iu_dst[e] - n_items;
                aux = iu_src[e];
            } else {
                long e = t - E_kg - E_iu;
                slot = S1 + SU + ui_dst[e];
                aux = ui_src[e];
            }
            int pos = atomicAdd(&off[slot >> BSH], 1);
            recA[pos] = make_int2(slot, aux);
        }
    }
}

// P4: per-bin fine sort: LDS hist over 512 slots -> deg/base + final scatter.
__global__ __launch_bounds__(256) void p4_sort_k(
        const int2* __restrict__ recA, const int* __restrict__ binStart,
        int2* __restrict__ recB, int* __restrict__ deg, int* __restrict__ base,
        int nbins) {
    int b = blockIdx.x, tid = threadIdx.x;
    int lane = tid & 63, w = tid >> 6;
    int lo = binStart[b], cnt = binStart[b + 1] - lo;
    __shared__ int h[512];
    __shared__ int pre[512];
    __shared__ int wtot[4];
    h[tid] = 0; h[tid + 256] = 0;
    __syncthreads();
    for (int i = tid; i < cnt; i += 256)
        atomicAdd(&h[recA[lo + i].x & 511], 1);
    __syncthreads();
    // scan chunk 1 (slots 0..255)
    int v1 = h[tid];
    int inc = v1;
#pragma unroll
    for (int off = 1; off < 64; off <<= 1) {
        int u = __shfl_up(inc, off);
        if (lane >= off) inc += u;
    }
    if (lane == 63) wtot[w] = inc;
    __syncthreads();
    int woff = 0;
    for (int i = 0; i < w; ++i) woff += wtot[i];
    int T1 = wtot[0] + wtot[1] + wtot[2] + wtot[3];
    int p1 = woff + inc - v1;
    __syncthreads();
    // scan chunk 2 (slots 256..511)
    int v2 = h[tid + 256];
    inc = v2;
#pragma unroll
    for (int off = 1; off < 64; off <<= 1) {
        int u = __shfl_up(inc, off);
        if (lane >= off) inc += u;
    }
    if (lane == 63) wtot[w] = inc;
    __syncthreads();
    woff = 0;
    for (int i = 0; i < w; ++i) woff += wtot[i];
    int p2 = T1 + woff + inc - v2;
    pre[tid] = p1; pre[tid + 256] = p2;
    int slot0 = (b << BSH) + tid;
    deg[slot0] = v1;       base[slot0] = lo + p1;
    deg[slot0 + 256] = v2; base[slot0 + 256] = lo + p2;
    __syncthreads();
    for (int i = tid; i < cnt; i += 256) {
        int2 r = recA[lo + i];
        int p = atomicAdd(&pre[r.x & 511], 1);
        recB[lo + p] = r;
    }
}

// ---------------- KG path ----------------

// Merged dots+chain in CSR (slot) order; 4 lanes/edge coalesced reads,
// 2-step shfl reduce, fast-math chain; payload write coalesced at slot.
__global__ __launch_bounds__(256) void kg_edge_fused_k(const float* __restrict__ ent,
                          const float* __restrict__ rel,
                          const int2* __restrict__ rec,
                          float4* __restrict__ payload,
                          int nE) {
    int w = blockIdx.x * 4 + (threadIdx.x >> 6);
    int l = threadIdx.x & 63;
    int slot = w * 16 + (l >> 2);
    if (slot >= nE) return;
    int j0 = l & 3;
    int2 rc = rec[slot];
    int s = rc.x, d = rc.y & 0x3FFFF, ty = rc.y >> 18;
    const float4* pu = (const float4*)(ent + (size_t)s * 64);
    const float4* pv = (const float4*)(ent + (size_t)d * 64);
    const float4* pr = (const float4*)(rel + (size_t)ty * 64);

    float uu = 0.f, vv = 0.f, rr = 0.f, uv = 0.f, ur = 0.f, vr = 0.f;
#pragma unroll
    for (int i = 0; i < 4; ++i) {
        float4 a = pu[4 * i + j0], b = pv[4 * i + j0], c = pr[4 * i + j0];
        uu += dot4(a, a); vv += dot4(b, b); rr += dot4(c, c);
        uv += dot4(a, b); ur += dot4(a, c); vr += dot4(b, c);
    }
#pragma unroll
    for (int m = 1; m < 4; m <<= 1) {
        uu += __shfl_xor(uu, m);
        vv += __shfl_xor(vv, m);
        rr += __shfl_xor(rr, m);
        uv += __shfl_xor(uv, m);
        ur += __shfl_xor(ur, m);
        vr += __shfl_xor(vr, m);
    }

    float n0 = sqrtf(fmaxf(uu, EPSF));
    float cp = tanh_f(n0) * frcp(n0);
    float p2 = cp * cp * uu;
    float om_p2 = 1.f - p2;
    float lam = 2.f * frcp(fmaxf(om_p2, EPSF));

    float nv = sqrtf(fmaxf(vv, EPSF));
    float cd = tanh_f(0.5f * lam * nv) * frcp(nv);
    float wd2 = cd * cd * vv;
    float pwd = cp * cd * uv;
    float iDd = frcp(fmaxf(1.f + 2.f * pwd + p2 * wd2, EPSF));
    float a1 = (1.f + 2.f * pwd + wd2) * cp * iDd;
    float b1 = om_p2 * cd * iDd;

    float nr = sqrtf(fmaxf(rr, EPSF));
    float cr = tanh_f(0.5f * lam * nr) * frcp(nr);
    float wr2 = cr * cr * rr;
    float pwr = cp * cr * ur;
    float iDr = frcp(fmaxf(1.f + 2.f * pwr + p2 * wr2, EPSF));
    float a2 = (1.f + 2.f * pwr + wr2) * cp * iDr;
    float c2 = om_p2 * cr * iDr;

    float x2 = a1 * a1 * uu + 2.f * a1 * b1 * uv + b1 * b1 * vv;
    float y2 = a2 * a2 * uu + 2.f * a2 * c2 * ur + c2 * c2 * rr;
    float xy = a1 * a2 * uu + a1 * c2 * ur + b1 * a2 * uv + b1 * c2 * vr;
    float iden = frcp(fmaxf(1.f + 2.f * xy + x2 * y2, EPSF));
    float E = (1.f + 2.f * xy + y2) * iden;
    float F = (1.f - x2) * iden;
    float zu = E * a1 + F * a2;
    float zv = E * b1;
    float zr = F * c2;

    float z2 = zu * zu * uu + zv * zv * vv + zr * zr * rr
             + 2.f * (zu * zv * uv + zu * zr * ur + zv * zr * vr);
    float nz = sqrtf(fmaxf(z2, EPSF));
    if (nz > MAXN) {
        float sc = MAXN * frcp(nz);
        zu *= sc; zv *= sc; zr *= sc;
        z2 *= sc * sc;
    }

    float mxy = -cp * (zu * uu + zv * uv + zr * ur);
    float idenl = frcp(fmaxf(1.f + 2.f * mxy + p2 * z2, EPSF));
    float G = (1.f + 2.f * mxy + z2) * idenl;
    float H = om_p2 * idenl;
    float su = -G * cp + H * zu;
    float sv = H * zv;
    float sr = H * zr;

    float ns2 = su * su * uu + sv * sv * vv + sr * sr * rr
              + 2.f * (su * sv * uv + su * sr * ur + sv * sr * vr);
    float ns = sqrtf(fmaxf(ns2, EPSF));
    float k = fmaxf(om_p2, EPSF) * atanh_f(fminf(ns, MAXN)) * frcp(ns);

    if (j0 == 0) {
        payload[slot] = make_float4(k * sv, k * sr, k * su, __int_as_float(rc.y));
    }
}

// Wave handles TWO consecutive entities via their combined contiguous slot
// range (CSR bases are globally contiguous), 8-deep unroll -> 8 row loads in
// flight. Select accumulator by slot position. Also emits item-row norms.
__global__ void kg_gather_k(const float* __restrict__ ent,
                            const float* __restrict__ rel,
                            const int* __restrict__ deg,
                            const int* __restrict__ base,
                            const float4* __restrict__ payload,
                            float* __restrict__ out_final,
                            float* __restrict__ out_items,
                            float* __restrict__ normv,
                            int n_items, int n) {
    int w = blockIdx.x * (blockDim.x >> 6) + (threadIdx.x >> 6);
    int i0 = w * 2;
    if (i0 >= n) return;
    bool has1 = (i0 + 1 < n);
    int l = threadIdx.x & 63;
    int b0 = base[i0];
    int d0 = deg[i0];
    int d1 = has1 ? deg[i0 + 1] : 0;
    int cnt = d0 + d1;
    int split = b0 + d0;
    float acc0 = 0.f, as0 = 0.f, acc1 = 0.f, as1 = 0.f;
    int q = 0;
    for (; q + 8 <= cnt; q += 8) {
        float4 p[8]; float vv[8], rr_[8];
#pragma unroll
        for (int j = 0; j < 8; ++j) p[j] = payload[b0 + q + j];
#pragma unroll
        for (int j = 0; j < 8; ++j) {
            int wd = __float_as_int(p[j].w);
            vv[j] = ent[(size_t)(wd & 0x3FFFF) * 64 + l];
            rr_[j] = rel[(size_t)(wd >> 18) * 64 + l];
        }
#pragma unroll
        for (int j = 0; j < 8; ++j) {
            float t = p[j].x * vv[j] + p[j].y * rr_[j];
            bool s0 = (b0 + q + j) < split;
            acc0 += s0 ? t : 0.f;
            acc1 += s0 ? 0.f : t;
            as0 += s0 ? p[j].z : 0.f;
            as1 += s0 ? 0.f : p[j].z;
        }
    }
    for (; q < cnt; ++q) {
        float4 p = payload[b0 + q];
        int wd = __float_as_int(p.w);
        float t = p.x * ent[(size_t)(wd & 0x3FFFF) * 64 + l]
                + p.y * rel[(size_t)(wd >> 18) * 64 + l];
        bool s0 = (b0 + q) < split;
        acc0 += s0 ? t : 0.f;
        acc1 += s0 ? 0.f : t;
        as0 += s0 ? p.z : 0.f;
        as1 += s0 ? 0.f : p.z;
    }
    {
        float v = (acc0 + as0 * ent[(size_t)i0 * 64 + l]) * frcp(fmaxf((float)d0, 1.f));
        if (i0 < n_items) {
            out_items[(size_t)i0 * 64 + l] = v;
            float s2 = wsum64(v * v);
            if (l == 0) normv[i0] = s2;
        } else {
            out_final[(size_t)i0 * 64 + l] = v;
        }
    }
    if (has1) {
        int i1 = i0 + 1;
        float v = (acc1 + as1 * ent[(size_t)i1 * 64 + l]) * frcp(fmaxf((float)d1, 1.f));
        if (i1 < n_items) {
            out_items[(size_t)i1 * 64 + l] = v;
            float s2 = wsum64(v * v);
            if (l == 0) normv[i1] = s2;
        } else {
            out_final[(size_t)i1 * 64 + l] = v;
        }
    }
}

// norms for the user half of cat_nodes
__global__ void user_norm_k(const float* __restrict__ user, float* __restrict__ normv,
                            int n_items, int n_usr) {
    int j = blockIdx.x * (blockDim.x >> 6) + (threadIdx.x >> 6);
    if (j >= n_usr) return;
    int l = threadIdx.x & 63;
    float c = user[(size_t)j * 64 + l];
    float s = wsum64(c * c);
    if (l == 0) normv[n_items + j] = s;
}

// ---------------- CF path ----------------

// Wave = 2 consecutive users, combined contiguous range, 8-deep unroll.
__global__ void iu_gather_k(const float* __restrict__ items, const float* __restrict__ user,
                            const int* __restrict__ deg, const int* __restrict__ base,
                            const int2* __restrict__ rec,
                            float* __restrict__ out_u, int n_items, int n, int SOFF) {
    int w = blockIdx.x * (blockDim.x >> 6) + (threadIdx.x >> 6);
    int i0 = w * 2;
    if (i0 >= n) return;
    bool has1 = (i0 + 1 < n);
    int l = threadIdx.x & 63;
    int b0 = base[SOFF + i0];
    int d0 = deg[SOFF + i0];
    int d1 = has1 ? deg[SOFF + i0 + 1] : 0;
    int cnt = d0 + d1;
    int split = b0 + d0;
    float acc0 = 0.f, acc1 = 0.f;
    int q = 0;
    for (; q + 8 <= cnt; q += 8) {
        float vs[8]; bool s0[8];
#pragma unroll
        for (int j = 0; j < 8; ++j) {
            int sidx = rec[b0 + q + j].y;
            vs[j] = (sidx < n_items) ? items[(size_t)sidx * 64 + l]
                                     : user[(size_t)(sidx - n_items) * 64 + l];
            s0[j] = (b0 + q + j) < split;
        }
#pragma unroll
        for (int j = 0; j < 8; ++j) {
            acc0 += s0[j] ? vs[j] : 0.f;
            acc1 += s0[j] ? 0.f : vs[j];
        }
    }
    for (; q < cnt; ++q) {
        int sidx = rec[b0 + q].y;
        float v = (sidx < n_items) ? items[(size_t)sidx * 64 + l]
                                   : user[(size_t)(sidx - n_items) * 64 + l];
        bool s0 = (b0 + q) < split;
        acc0 += s0 ? v : 0.f;
        acc1 += s0 ? 0.f : v;
    }
    out_u[(size_t)i0 * 64 + l] = acc0 * frcp(fmaxf((float)d0, 1.f));
    if (has1)
        out_u[(size_t)(i0 + 1) * 64 + l] = acc1 * frcp(fmaxf((float)d1, 1.f));
}

// Wave = 2 consecutive items, combined range, 8-deep unroll:
// icf[i] = norm[i]*(sum cat[s]/(norm[s]+1e-6))/deg
__global__ void ui_gather_k(const float* __restrict__ items, const float* __restrict__ user,
                            const float* __restrict__ normv,
                            const int* __restrict__ deg, const int* __restrict__ base,
                            const int2* __restrict__ rec,
                            float* __restrict__ icf, int n_items, int n, int SOFF) {
    int w = blockIdx.x * (blockDim.x >> 6) + (threadIdx.x >> 6);
    int i0 = w * 2;
    if (i0 >= n) return;
    bool has1 = (i0 + 1 < n);
    int l = threadIdx.x & 63;
    int b0 = base[SOFF + i0];
    int d0 = deg[SOFF + i0];
    int d1 = has1 ? deg[SOFF + i0 + 1] : 0;
    int cnt = d0 + d1;
    int split = b0 + d0;
    float acc0 = 0.f, acc1 = 0.f;
    int q = 0;
    for (; q + 8 <= cnt; q += 8) {
        int ss[8]; float fs[8], vs[8]; bool s0[8];
#pragma unroll
        for (int j = 0; j < 8; ++j) ss[j] = rec[b0 + q + j].y;
#pragma unroll
        for (int j = 0; j < 8; ++j) fs[j] = frcp(normv[ss[j]] + 1e-6f);
#pragma unroll
        for (int j = 0; j < 8; ++j) {
            int sidx = ss[j];
            vs[j] = (sidx < n_items) ? items[(size_t)sidx * 64 + l]
                                     : user[(size_t)(sidx - n_items) * 64 + l];
            s0[j] = (b0 + q + j) < split;
        }
#pragma unroll
        for (int j = 0; j < 8; ++j) {
            float t = fs[j] * vs[j];
            acc0 += s0[j] ? t : 0.f;
            acc1 += s0[j] ? 0.f : t;
        }
    }
    for (; q < cnt; ++q) {
        int sidx = rec[b0 + q].y;
        float f = frcp(normv[sidx] + 1e-6f);
        float t = f * ((sidx < n_items) ? items[(size_t)sidx * 64 + l]
                                        : user[(size_t)(sidx - n_items) * 64 + l]);
        bool s0 = (b0 + q) < split;
        acc0 += s0 ? t : 0.f;
        acc1 += s0 ? 0.f : t;
    }
    icf[(size_t)i0 * 64 + l] = normv[i0] * acc0 * frcp(fmaxf((float)d0, 1.f));
    if (has1)
        icf[(size_t)(i0 + 1) * 64 + l] =
            normv[i0 + 1] * acc1 * frcp(fmaxf((float)d1, 1.f));
}

// MFMA gate+fusion: acc = [oi|cf] @ [W1;W2]^T (bf16), out = g*oi + (1-g)*cf.
__global__ __launch_bounds__(256) void fusion_mfma_k(const float* __restrict__ items,
                          const float* __restrict__ icf,
                          const float* __restrict__ W1, const float* __restrict__ W2,
                          float* __restrict__ outf, int n_items) {
    int lane = threadIdx.x & 63;
    int row0 = blockIdx.x * 64 + (threadIdx.x >> 6) * 16;
    int r = lane & 15, g = lane >> 4;

    int arow = row0 + r;
    size_t rbase = (size_t)(arow < n_items ? arow : 0) * 64;

    bf16x8 afrag[4];
#pragma unroll
    for (int s = 0; s < 4; ++s) {
        int kb = s * 32 + g * 8;
        const float* p = (kb < 64) ? (items + rbase + kb) : (icf + rbase + kb - 64);
        afrag[s] = pack8(p);
    }

    bf16x8 bfrag[4][4];
#pragma unroll
    for (int c = 0; c < 4; ++c) {
        int col = c * 16 + r;
#pragma unroll
        for (int s = 0; s < 4; ++s) {
            int kb = s * 32 + g * 8;
            const float* p = (kb < 64) ? (W1 + col * 64 + kb) : (W2 + col * 64 + kb - 64);
            bfrag[c][s] = pack8(p);
        }
    }

    f32x4 acc[4] = {{0.f,0.f,0.f,0.f},{0.f,0.f,0.f,0.f},
                    {0.f,0.f,0.f,0.f},{0.f,0.f,0.f,0.f}};
#pragma unroll
    for (int s = 0; s < 4; ++s)
#pragma unroll
        for (int c = 0; c < 4; ++c)
            acc[c] = __builtin_amdgcn_mfma_f32_16x16x32_bf16(afrag[s], bfrag[c][s],
                                                             acc[c], 0, 0, 0);

#pragma unroll
    for (int c = 0; c < 4; ++c) {
        int col = c * 16 + r;
#pragma unroll
        for (int q = 0; q < 4; ++q) {
            int orow = row0 + g * 4 + q;
            if (orow < n_items) {
                size_t off = (size_t)orow * 64 + col;
                float oi = items[off], cf = icf[off];
                float gate = frcp(1.f + __expf(-acc[c][q]));
                outf[off] = gate * oi + (1.f - gate) * cf;
            }
        }
    }
}

extern "C" void kernel_launch(void* const* d_in, const int* in_sizes, int n_in,
                              void* d_out, int out_size, void* d_ws, size_t ws_size,
                              hipStream_t stream) {
    const float* ent    = (const float*)d_in[0];
    const float* usr    = (const float*)d_in[1];
    const float* rel    = (const float*)d_in[2];
    const float* W1     = (const float*)d_in[3];
    const float* W2     = (const float*)d_in[4];
    const int*   kg_src = (const int*)d_in[5];
    const int*   kg_dst = (const int*)d_in[6];
    const int*   kg_typ = (const int*)d_in[7];
    const int*   iu_src = (const int*)d_in[8];
    const int*   iu_dst = (const int*)d_in[9];
    const int*   ui_src = (const int*)d_in[10];
    const int*   ui_dst = (const int*)d_in[11];

    const int n_ent   = in_sizes[0] / 64;
    const int n_usr   = in_sizes[1] / 64;
    const int E_kg    = in_sizes[5];
    const int E_iu    = in_sizes[8];
    const int E_ui    = in_sizes[10];
    const int n_items = (out_size - in_sizes[0] - in_sizes[1]) / 64;
    const int N       = n_items + n_usr;

    // unified slot space: [ent | user | item], each 512-aligned
    const int S1 = ((n_ent + 511) / 512) * 512;
    const int SU = ((n_usr + 511) / 512) * 512;
    const int SI = ((n_items + 511) / 512) * 512;
    const int S3 = S1 + SU + SI;
    const int nbins = S3 >> BSH;
    const long tot = (long)E_kg + E_iu + E_ui;
    const int NBLK = (int)((tot + 2047) / 2048);

    float* out_final = (float*)d_out;                        // (n_ent,64)
    float* out_u     = out_final + (size_t)n_ent * 64;       // (n_usr,64)
    float* out_items = out_u + (size_t)n_usr * 64;           // (n_items,64)

    // d_out tail scratch (dead before kg/iu gathers write these chunks):
    // recA = bin-grouped intermediate records (tot*8B), H after it.
    int2* recA = (int2*)out_u;                               // tot * 8B
    int*  H    = (int*)(recA + tot);                         // NBLK*nbins*4B

    float* ws = (float*)d_ws;
    size_t o = 0;
    int* binTotal = (int*)(ws + o); o += nbins;
    int* binStart = (int*)(ws + o); o += nbins + 1;
    int* deg      = (int*)(ws + o); o += S3;
    int* basep    = (int*)(ws + o); o += S3;
    o = (o + 3) & ~(size_t)3;                      // 16B align
    int2* recB    = (int2*)(ws + o); o += (size_t)tot * 2;
    float4* pay_kg = (float4*)(ws + o); o += (size_t)E_kg * 4;
    float* icf    = (float*)pay_kg;   // alias: pay_kg dead after kg_gather
    float* normv  = ws + o; o += N;

    // CSR build (all LDS atomics; no memsets - every buffer fully written)
    p1_hist_k<<<NBLK, 256, 0, stream>>>(kg_src, iu_dst, ui_dst, H,
                                        E_kg, E_iu, E_ui, n_items, S1, SU, nbins);
    p2a_scan_k<<<nbins, 256, 0, stream>>>(H, binTotal, NBLK, nbins);
    p2b_bins_k<<<1, 512, 0, stream>>>(binTotal, binStart, nbins);
    p3_scat_k<<<NBLK, 256, 0, stream>>>(kg_src, kg_dst, kg_typ, iu_src, iu_dst,
                                        ui_src, ui_dst, H, binStart, recA,
                                        E_kg, E_iu, E_ui, n_items, S1, SU, nbins);
    p4_sort_k<<<nbins, 256, 0, stream>>>(recA, binStart, recB, deg, basep, nbins);

    // KG compute (CSR-ordered edge pass; kg records = recB[0..E_kg))
    kg_edge_fused_k<<<(E_kg + 63) / 64, 256, 0, stream>>>(ent, rel, recB,
                                                          pay_kg, E_kg);
    int wv_e = (n_ent + 1) / 2;
    kg_gather_k<<<(wv_e + 3) / 4, 256, 0, stream>>>(ent, rel, deg, basep, pay_kg,
                                                    out_final, out_items, normv,
                                                    n_items, n_ent);
    user_norm_k<<<(n_usr + 3) / 4, 256, 0, stream>>>(usr, normv, n_items, n_usr);

    // CF gathers (direct output writes; recA/H in d_out are dead by now)
    int wv_u = (n_usr + 1) / 2;
    iu_gather_k<<<(wv_u + 3) / 4, 256, 0, stream>>>(out_items, usr, deg, basep,
                                                    recB, out_u, n_items, n_usr, S1);
    int wv_i = (n_items + 1) / 2;
    ui_gather_k<<<(wv_i + 3) / 4, 256, 0, stream>>>(out_items, usr, normv, deg,
                                                    basep, recB, icf, n_items,
                                                    n_items, S1 + SU);
    fusion_mfma_k<<<(n_items + 63) / 64, 256, 0, stream>>>(out_items, icf, W1, W2,
                                                           out_final, n_items);
}